// Round 12
// baseline (481.651 us; speedup 1.0000x reference)
//
#include <hip/hip_runtime.h>
#include <stdint.h>

// ---------------------------------------------------------------------------
// RULSTM collapsed: y = h2 @ Wc.T + bc, h2 = 2 unroll steps from rolling-LSTM
// final state. Gate axis permuted (n_new=(j&15)|gate<<4|(j>>4)<<6) so the LSTM
// cell fuses into the GEMM epilogue.
// r12: base = r10 (best, 447us). One change: step kernel A-operand (h rows,
// wave-private) now loads DIRECT from global into a register double-buffer
// (prefetched one chunk ahead) -- sA, its 2 gload_lds/chunk and the LDS
// round-trip are gone. W keeps the r10-proven 4-buffer depth-3 counted-vmcnt
// pipeline + swizzled ds_read (verbatim). LDS 64->32 KB. r9/r11 lesson
// (2 blk/CU mandatory) preserved: same 64x64 tile, grid (64,8), 256 thr.
// ---------------------------------------------------------------------------

typedef __attribute__((ext_vector_type(8))) short short8;
typedef __attribute__((ext_vector_type(4))) float f32x4;

#define SEQ   16
#define BATCH 512
#define HID   1024
#define GATE4 4096
#define FEAT  2048
#define ACTN  2513
#define ACTP  2560
#define SB    (SEQ * BATCH)   // 8192

#define VMCNT0 asm volatile("s_waitcnt vmcnt(0)" ::: "memory")
#define BAR    __builtin_amdgcn_s_barrier()
#define SCHED0 __builtin_amdgcn_sched_barrier(0)
#define WAITV(n) asm volatile("s_waitcnt vmcnt(" #n ")" ::: "memory")

__device__ __forceinline__ unsigned short f2bf(float x) {
    unsigned u = __float_as_uint(x);
    u = u + 0x7FFFu + ((u >> 16) & 1u);
    return (unsigned short)(u >> 16);
}
__device__ __forceinline__ float bf2f(unsigned short h) {
    return __uint_as_float(((unsigned)h) << 16);
}
__device__ __forceinline__ float sigm(float x) { return 1.f / (1.f + __expf(-x)); }

__device__ __forceinline__ int gate_unperm(int nn) {
    return (((nn >> 4) & 3) << 10) | ((nn >> 6) << 4) | (nn & 15);
}

__device__ __forceinline__ void gload_lds16(const void* g, void* l) {
    __builtin_amdgcn_global_load_lds(
        (const __attribute__((address_space(1))) void*)g,
        (__attribute__((address_space(3))) void*)l,
        16, 0, 0);
}

// ---------------------------------------------------------------------------
// Generic C[M,N] = A[M,K]@W[N,K]^T (+bias), 128x128 tile, 2-phase dbuf,
// XOR-swizzled LDS (swizzle on global source; dest linear). r7-proven.
// ---------------------------------------------------------------------------
template<bool OUT_BF16, bool HAS_BIAS, bool GUARD>
__global__ __launch_bounds__(256)
void gemm_bt(const unsigned short* __restrict__ A,
             const unsigned short* __restrict__ W,
             void* __restrict__ Cv,
             const float* __restrict__ bias,
             int M, int N, int K, int ldc, int nvalid)
{
    __shared__ __align__(16) unsigned short sA[2][128 * 64];
    __shared__ __align__(16) unsigned short sB[2][128 * 64];

    const int t    = threadIdx.x;
    const int lane = t & 63;
    const int wave = t >> 6;
    const int m0   = blockIdx.y * 128;
    const int n0   = blockIdx.x * 128;
    const int srow = t >> 3;                       // 0..31
    const int schk = t & 7;                        // linear LDS chunk
    const int swc  = (schk ^ (srow & 7)) * 8;      // swizzled global col (elems)
    const int sdst = srow * 64 + schk * 8;         // linear LDS dest (elems)
    const int wm   = (wave >> 1) * 64;
    const int wn   = (wave & 1) * 64;
    const int fl   = lane & 15;
    const int fk8  = (lane >> 4) * 8;              // 0 or 8
    const int l7   = lane & 7;                     // row&7 for fragment reads

    f32x4 acc[4][4] = {};

    const unsigned short* Abase = A + (size_t)(m0 + srow) * K + swc;
    const unsigned short* Wbase = W + (size_t)(n0 + srow) * K + swc;

    const int nkt = K >> 6;

#define G_STAGE(kt, buf)                                                     \
    {                                                                        \
        _Pragma("unroll")                                                    \
        for (int j = 0; j < 4; ++j) {                                        \
            gload_lds16(Abase + (size_t)j * 32 * K + (kt) * 64,              \
                        &sA[buf][sdst + j * 32 * 64]);                       \
            gload_lds16(Wbase + (size_t)j * 32 * K + (kt) * 64,              \
                        &sB[buf][sdst + j * 32 * 64]);                       \
        }                                                                    \
    }

    G_STAGE(0, 0);
    VMCNT0; BAR; SCHED0;

    int cur = 0;
    for (int kt = 0; kt < nkt; ++kt) {
        if (kt + 1 < nkt) G_STAGE(kt + 1, cur ^ 1);
        const unsigned short* sa = sA[cur];
        const unsigned short* sb = sB[cur];
#pragma unroll
        for (int kk = 0; kk < 64; kk += 32) {
            const int cs = (((kk + fk8) >> 3) ^ l7) * 8;  // swizzled read col
            short8 af[4], bfrag[4];
#pragma unroll
            for (int i = 0; i < 4; ++i)
                af[i] = *(const short8*)&sa[(wm + i * 16 + fl) * 64 + cs];
#pragma unroll
            for (int i = 0; i < 4; ++i)
                bfrag[i] = *(const short8*)&sb[(wn + i * 16 + fl) * 64 + cs];
#pragma unroll
            for (int mi = 0; mi < 4; ++mi)
#pragma unroll
                for (int ni = 0; ni < 4; ++ni)
                    acc[mi][ni] = __builtin_amdgcn_mfma_f32_16x16x32_bf16(
                        af[mi], bfrag[ni], acc[mi][ni], 0, 0, 0);
        }
        VMCNT0; BAR; SCHED0;
        cur ^= 1;
    }
#undef G_STAGE

    const int crb = (lane >> 4) * 4;
#pragma unroll
    for (int mi = 0; mi < 4; ++mi) {
#pragma unroll
        for (int ni = 0; ni < 4; ++ni) {
            const int col = n0 + wn + ni * 16 + fl;
            if (GUARD && col >= nvalid) continue;
            const float bv = HAS_BIAS ? bias[col] : 0.0f;
#pragma unroll
            for (int r = 0; r < 4; ++r) {
                const int row = m0 + wm + mi * 16 + crb + r;
                float v = acc[mi][ni][r] + bv;
                if (OUT_BF16)
                    ((unsigned short*)Cv)[(size_t)row * ldc + col] = f2bf(v);
                else
                    ((float*)Cv)[(size_t)row * ldc + col] = v;
            }
        }
    }
}

// ---------------------------------------------------------------------------
// Fused LSTM step: r10 shape (64x64 tile, grid (64,8), 256 thr, 2 blk/CU).
// A (h rows, wave-private) read DIRECT from global into a prefetched register
// double-buffer; W keeps 4-buffer depth-3 counted-vmcnt LDS pipeline with
// swizzled ds_read (r10-verbatim formulas). LDS = 32 KiB (W only).
// ---------------------------------------------------------------------------
template<bool HAS_BIAS>
__global__ __launch_bounds__(256)
void lstm_step_fused(const unsigned short* __restrict__ hin,  // [512,1024] bf16
                     const unsigned short* __restrict__ W,    // [4096,1024] perm
                     const unsigned short* __restrict__ xg,   // [512,4096] perm
                     const float* __restrict__ bias,          // [4096] perm/null
                     float* __restrict__ c,                   // [512,1024] f32
                     unsigned short* __restrict__ hout)       // [512,1024] bf16
{
    __shared__ __align__(16) unsigned short sB[4][64 * 64];   // 32 KiB

    const int t    = threadIdx.x;
    const int lane = t & 63;
    const int wave = t >> 6;          // 0..3, 16 rows each
    const int m0   = blockIdx.y * 64;
    const int n0   = blockIdx.x * 64;
    const int srow = t >> 3;          // 0..31
    const int schk = t & 7;
    const int swc  = (schk ^ (srow & 7)) * 8;
    const int sdst = srow * 64 + schk * 8;
    const int wm   = wave * 16;
    const int fl   = lane & 15;
    const int fk8  = (lane >> 4) * 8;
    const int l7   = lane & 7;

    f32x4 acc[4] = {};

    // per-lane A row pointer (wave-private rows m0+wm .. m0+wm+15)
    const unsigned short* Arow  = hin + (size_t)(m0 + wm + fl) * HID + fk8;
    const unsigned short* Wbase = W + (size_t)(n0 + srow) * HID + swc;

#define SW(kt)                                                               \
    {                                                                        \
        const int _b = (kt) & 3;                                             \
        _Pragma("unroll")                                                    \
        for (int j = 0; j < 2; ++j)                                          \
            gload_lds16(Wbase + (size_t)j * 32 * HID + (kt) * 64,            \
                        &sB[_b][sdst + j * 32 * 64]);                        \
    }

#define LA0(kt) (*(const short8*)(Arow + (size_t)(kt) * 64))
#define LA1(kt) (*(const short8*)(Arow + (size_t)(kt) * 64 + 32))

#define S_COMP(kt, a0, a1)                                                   \
    {                                                                        \
        const unsigned short* sb = sB[(kt) & 3];                             \
        {                                                                    \
            const int cs = ((fk8 >> 3) ^ l7) * 8;                            \
            _Pragma("unroll")                                                \
            for (int ni = 0; ni < 4; ++ni) {                                 \
                short8 bfr = *(const short8*)&sb[(ni * 16 + fl) * 64 + cs];  \
                acc[ni] = __builtin_amdgcn_mfma_f32_16x16x32_bf16(           \
                    (a0), bfr, acc[ni], 0, 0, 0);                            \
            }                                                                \
        }                                                                    \
        {                                                                    \
            const int cs = (((32 + fk8) >> 3) ^ l7) * 8;                     \
            _Pragma("unroll")                                                \
            for (int ni = 0; ni < 4; ++ni) {                                 \
                short8 bfr = *(const short8*)&sb[(ni * 16 + fl) * 64 + cs];  \
                acc[ni] = __builtin_amdgcn_mfma_f32_16x16x32_bf16(           \
                    (a1), bfr, acc[ni], 0, 0, 0);                            \
            }                                                                \
        }                                                                    \
    }

    SW(0); SW(1); SW(2);                 // 6 W loads in flight
    short8 ac0 = LA0(0), ac1 = LA1(0);   // A(0) prefetch

    for (int kt = 0; kt < 13; ++kt) {
        short8 an0 = LA0(kt + 1), an1 = LA1(kt + 1);   // prefetch A(kt+1)
        WAITV(8); BAR; SCHED0;           // W(kt) resident (10 newer VMEM ops)
        SW(kt + 3);                      // stages 3..15
        S_COMP(kt, ac0, ac1);
        ac0 = an0; ac1 = an1;
    }
    // tail: all W staged; load remaining A, drain once, compute 13..15
    {
        short8 a14_0 = LA0(14), a14_1 = LA1(14);
        short8 a15_0 = LA0(15), a15_1 = LA1(15);
        VMCNT0; BAR; SCHED0;
        S_COMP(13, ac0, ac1);
        S_COMP(14, a14_0, a14_1);
        S_COMP(15, a15_0, a15_1);
    }
#undef SW
#undef LA0
#undef LA1
#undef S_COMP

    // fused cell epilogue: ni = gate (0:i 1:f 2:g 3:o), j = (n0>>6)*16 + fl
    const int crb = (lane >> 4) * 4;
    const int jj  = (n0 >> 6) * 16 + fl;
    float bv[4] = {0.f, 0.f, 0.f, 0.f};
    if (HAS_BIAS) {
#pragma unroll
        for (int ni = 0; ni < 4; ++ni) bv[ni] = bias[n0 + ni * 16 + fl];
    }
#pragma unroll
    for (int r = 0; r < 4; ++r) {
        const int b = m0 + wm + crb + r;
        float v[4];
#pragma unroll
        for (int ni = 0; ni < 4; ++ni)
            v[ni] = acc[ni][r] + bv[ni] + bf2f(xg[(size_t)b * GATE4 + n0 + ni * 16 + fl]);
        const int ci = b * HID + jj;
        float cv = sigm(v[1]) * c[ci] + sigm(v[0]) * tanhf(v[2]);
        c[ci] = cv;
        hout[ci] = f2bf(sigm(v[3]) * tanhf(cv));
    }
}

// ---------------------------------------------------------------------------
// Step 0 of rolling LSTM (h=0, c=0): pure cell on xg_r[0] + bhh
// ---------------------------------------------------------------------------
__global__ void lstm_cell0_k(const unsigned short* __restrict__ xg,
                             const float* __restrict__ bias,
                             float* __restrict__ c, unsigned short* __restrict__ h)
{
    int idx = blockIdx.x * blockDim.x + threadIdx.x;  // < 512*1024
    int b = idx >> 10, j = idx & 1023;
    int base = (j & 15) | ((j >> 4) << 6);
    float v[4];
#pragma unroll
    for (int g = 0; g < 4; ++g) {
        int col = base | (g << 4);
        v[g] = bf2f(xg[(size_t)b * GATE4 + col]) + bias[col];
    }
    float cv = sigm(v[0]) * tanhf(v[2]);   // c_prev = 0
    c[idx] = cv;
    h[idx] = f2bf(sigm(v[3]) * tanhf(cv));
}

// ---------------------------------------------------------------------------
// One merged prep kernel (all conversions/permutations/folds)
// ---------------------------------------------------------------------------
#define PB_IN   16384
#define PB_W1   (PB_IN + 2048)       // 18432
#define PB_WR   (PB_W1 + 4096)       // 22528
#define PB_WU   (PB_WR + 4096)       // 26624
#define PB_WHR  (PB_WU + 4096)       // 30720
#define PB_WHU  (PB_WHR + 4096)      // 34816
#define PB_WC   (PB_WHU + 2560)      // 37376
#define PB_END  (PB_WC + 26)         // 37402

__device__ __forceinline__ void cvt4(const float* src, unsigned short* dst) {
    float4 v = *(const float4*)src;
    ushort4 o;
    o.x = f2bf(v.x); o.y = f2bf(v.y); o.z = f2bf(v.z); o.w = f2bf(v.w);
    *(ushort4*)dst = o;
}

__global__ void prep_all_k(const float* __restrict__ inputs, const float* __restrict__ W1,
                           const float* __restrict__ Wih_r, const float* __restrict__ Wih_u,
                           const float* __restrict__ Whh_r, const float* __restrict__ Whh_u,
                           const float* __restrict__ Wc,
                           const float* __restrict__ bih_r, const float* __restrict__ bhh_r,
                           const float* __restrict__ bih_u, const float* __restrict__ bhh_u,
                           const float* __restrict__ bc,
                           unsigned short* __restrict__ in_bf, unsigned short* __restrict__ W1b,
                           unsigned short* __restrict__ Wrb, unsigned short* __restrict__ Wub,
                           unsigned short* __restrict__ Whhrb, unsigned short* __restrict__ Whhub,
                           unsigned short* __restrict__ Wcb,
                           float* __restrict__ bihr_p, float* __restrict__ bhhr_p,
                           float* __restrict__ bu_p, float* __restrict__ bc_p)
{
    const int blk = blockIdx.x, tid = threadIdx.x;
    if (blk < PB_IN) {                       // inputs f32 -> bf16 (8192x2048)
        int i = blk * 256 + tid;
        cvt4(inputs + (size_t)i * 4, in_bf + (size_t)i * 4);
    } else if (blk < PB_W1) {                // W1 f32 -> bf16 (1024x2048)
        int i = (blk - PB_IN) * 256 + tid;
        cvt4(W1 + (size_t)i * 4, W1b + (size_t)i * 4);
    } else if (blk < PB_WR) {                // Wih_r: sum halves + perm
        int i = (blk - PB_W1) * 256 + tid;
        int nn = i >> 8, k4 = (i & 255) * 4;
        const float* row = Wih_r + (size_t)gate_unperm(nn) * FEAT;
        float4 a = *(const float4*)(row + k4);
        float4 b = *(const float4*)(row + HID + k4);
        ushort4 o;
        o.x = f2bf(a.x + b.x); o.y = f2bf(a.y + b.y);
        o.z = f2bf(a.z + b.z); o.w = f2bf(a.w + b.w);
        *(ushort4*)(Wrb + (size_t)nn * HID + k4) = o;
    } else if (blk < PB_WU) {                // Wih_u: sum halves + perm
        int i = (blk - PB_WR) * 256 + tid;
        int nn = i >> 8, k4 = (i & 255) * 4;
        const float* row = Wih_u + (size_t)gate_unperm(nn) * FEAT;
        float4 a = *(const float4*)(row + k4);
        float4 b = *(const float4*)(row + HID + k4);
        ushort4 o;
        o.x = f2bf(a.x + b.x); o.y = f2bf(a.y + b.y);
        o.z = f2bf(a.z + b.z); o.w = f2bf(a.w + b.w);
        *(ushort4*)(Wub + (size_t)nn * HID + k4) = o;
    } else if (blk < PB_WHR) {               // Whh_r perm
        int i = (blk - PB_WU) * 256 + tid;
        int nn = i >> 8, k4 = (i & 255) * 4;
        cvt4(Whh_r + (size_t)gate_unperm(nn) * HID + k4, Whhrb + (size_t)nn * HID + k4);
    } else if (blk < PB_WHU) {               // Whh_u perm
        int i = (blk - PB_WHR) * 256 + tid;
        int nn = i >> 8, k4 = (i & 255) * 4;
        cvt4(Whh_u + (size_t)gate_unperm(nn) * HID + k4, Whhub + (size_t)nn * HID + k4);
    } else if (blk < PB_WC) {                // Wc pad to 2560 rows
        int i = (blk - PB_WHU) * 256 + tid;
        int g = i >> 8, k4 = (i & 255) * 4;
        if (g < ACTN) {
            cvt4(Wc + (size_t)g * HID + k4, Wcb + (size_t)g * HID + k4);
        } else {
            ushort4 o; o.x = o.y = o.z = o.w = 0;
            *(ushort4*)(Wcb + (size_t)g * HID + k4) = o;
        }
    } else {                                 // biases (4096 perm + 2560 bc)
        int i = (blk - PB_WC) * 256 + tid;
        if (i < GATE4) {
            int src = gate_unperm(i);
            bihr_p[i] = bih_r[src];
            bhhr_p[i] = bhh_r[src];
            bu_p[i]   = bih_u[src] + bhh_u[src];
        } else if (i < GATE4 + ACTP) {
            int j = i - GATE4;
            bc_p[j] = (j < ACTN) ? bc[j] : 0.f;
        }
    }
}

// ---------------------------------------------------------------------------
// Workspace layout (bytes) — end 162,588,672 (proven footprint)
// ---------------------------------------------------------------------------
#define OFF_IN_BF 0ull
#define OFF_X_BF  33554432ull
#define OFF_XGR   50331648ull
#define OFF_W1    117440512ull
#define OFF_WR    121634816ull
#define OFF_WHHR  130023424ull
#define OFF_WU    138412032ull
#define OFF_WHHU  146800640ull
#define OFF_WCB   155189248ull      // 2560*1024*2 -> ends 160432128
#define OFF_H0    160432128ull      // 1 MiB
#define OFF_H1    161480704ull      // 1 MiB
#define OFF_BC    162529280ull
#define OFF_BU    162539520ull
#define OFF_BIHR  162555904ull
#define OFF_BHHR  162572288ull
// xg_u (4 MiB) and c_buf (2 MiB) overlay in_bf (dead after G1).

extern "C" void kernel_launch(void* const* d_in, const int* in_sizes, int n_in,
                              void* d_out, int out_size, void* d_ws, size_t ws_size,
                              hipStream_t stream)
{
    const float* inputs = (const float*)d_in[0];
    const float* W1     = (const float*)d_in[1];
    const float* b1     = (const float*)d_in[2];
    const float* Wih_r  = (const float*)d_in[3];
    const float* Whh_r  = (const float*)d_in[4];
    const float* bih_r  = (const float*)d_in[5];
    const float* bhh_r  = (const float*)d_in[6];
    const float* Wih_u  = (const float*)d_in[7];
    const float* Whh_u  = (const float*)d_in[8];
    const float* bih_u  = (const float*)d_in[9];
    const float* bhh_u  = (const float*)d_in[10];
    const float* Wc     = (const float*)d_in[11];
    const float* bc     = (const float*)d_in[12];
    float* out = (float*)d_out;
    char* ws = (char*)d_ws;

    unsigned short* in_bf = (unsigned short*)(ws + OFF_IN_BF);
    unsigned short* x_bf  = (unsigned short*)(ws + OFF_X_BF);
    unsigned short* xg_r  = (unsigned short*)(ws + OFF_XGR);
    unsigned short* W1b   = (unsigned short*)(ws + OFF_W1);
    unsigned short* Wrb   = (unsigned short*)(ws + OFF_WR);
    unsigned short* Whhrb = (unsigned short*)(ws + OFF_WHHR);
    unsigned short* Wub   = (unsigned short*)(ws + OFF_WU);
    unsigned short* Whhub = (unsigned short*)(ws + OFF_WHHU);
    unsigned short* Wcb   = (unsigned short*)(ws + OFF_WCB);
    unsigned short* h0    = (unsigned short*)(ws + OFF_H0);
    unsigned short* h1    = (unsigned short*)(ws + OFF_H1);
    float*          bc_p  = (float*)(ws + OFF_BC);
    float*          bu_p  = (float*)(ws + OFF_BU);
    float*          bihr_p= (float*)(ws + OFF_BIHR);
    float*          bhhr_p= (float*)(ws + OFF_BHHR);
    unsigned short* xg_u  = (unsigned short*)(ws + OFF_IN_BF);           // 4 MiB
    float*          c_buf = (float*)(ws + OFF_IN_BF + 4194304ull);      // 2 MiB

    const dim3 blk(256);

    // ---- prep (one launch) ----
    prep_all_k<<<dim3(PB_END), blk, 0, stream>>>(
        inputs, W1, Wih_r, Wih_u, Whh_r, Whh_u, Wc,
        bih_r, bhh_r, bih_u, bhh_u, bc,
        in_bf, W1b, Wrb, Wub, Whhrb, Whhub, Wcb,
        bihr_p, bhhr_p, bu_p, bc_p);

    // ---- G1: x = inputs @ W1^T + b1 -> bf16 [8192,1024] ----
    gemm_bt<true, true, false><<<dim3(HID / 128, SB / 128), blk, 0, stream>>>(
        in_bf, W1b, x_bf, b1, SB, HID, FEAT, HID, HID);

    // ---- G2: xg_r = x @ Wr_eff^T + bih_r -> bf16 [8192,4096] (perm cols) ----
    gemm_bt<true, true, false><<<dim3(GATE4 / 128, SB / 128), blk, 0, stream>>>(
        x_bf, Wrb, xg_r, bihr_p, SB, GATE4, HID, GATE4, GATE4);

    // ---- xg_u = x[15] @ Wu_eff^T + (bih_u + bhh_u) -> bf16 [512,4096] ----
    gemm_bt<true, true, false><<<dim3(GATE4 / 128, BATCH / 128), blk, 0, stream>>>(
        x_bf + (size_t)(SEQ - 1) * BATCH * HID, Wub, xg_u, bu_p,
        BATCH, GATE4, HID, GATE4, GATE4);

    // ---- rolling LSTM: step 0 pure cell (h=c=0), then 15 fused steps ----
    lstm_cell0_k<<<dim3(BATCH * HID / 256), blk, 0, stream>>>(xg_r, bhhr_p, c_buf, h0);
    unsigned short* hc = h0;
    unsigned short* hn = h1;
    for (int s = 1; s < SEQ; ++s) {
        lstm_step_fused<true><<<dim3(GATE4 / 64, BATCH / 64), blk, 0, stream>>>(
            hc, Whhrb, xg_r + (size_t)s * BATCH * GATE4, bhhr_p, c_buf, hn);
        unsigned short* tmp = hc; hc = hn; hn = tmp;
    }

    // ---- 2 unroll steps (bias folded into xg_u) ----
    for (int s = 0; s < 2; ++s) {
        lstm_step_fused<false><<<dim3(GATE4 / 64, BATCH / 64), blk, 0, stream>>>(
            hc, Whhub, xg_u, nullptr, c_buf, hn);
        unsigned short* tmp = hc; hc = hn; hn = tmp;
    }

    // ---- classifier: y = h @ Wc^T + bc -> fp32 [512,2513] ----
    gemm_bt<false, true, true><<<dim3(ACTP / 128, BATCH / 128), blk, 0, stream>>>(
        hc, Wcb, out, bc_p, BATCH, ACTP, HID, ACTN, ACTN);
}

// Round 13
// 442.286 us; speedup vs baseline: 1.0890x; 1.0890x over previous
//
#include <hip/hip_runtime.h>
#include <stdint.h>

// ---------------------------------------------------------------------------
// RULSTM collapsed: y = h2 @ Wc.T + bc, h2 = 2 unroll steps from rolling-LSTM
// final state. Gate axis permuted (n_new=(j&15)|gate<<4|(j>>4)<<6) so the LSTM
// cell fuses into the GEMM epilogue.
// r13: base = r10 (best, 447us; step kernel r10-verbatim -- r8/r9/r11/r12 all
// lost to it). One change: T1 XCD-aware block swizzle on G1/G2 (1-D grid,
// 8x8 super-tiles per XCD -> per-XCD L2 working set ~4MB, panels fetched once
// per XCD instead of 3.4x over-fetch through L3). Pure index remap, bitwise-
// identical output.
// ---------------------------------------------------------------------------

typedef __attribute__((ext_vector_type(8))) short short8;
typedef __attribute__((ext_vector_type(4))) float f32x4;

#define SEQ   16
#define BATCH 512
#define HID   1024
#define GATE4 4096
#define FEAT  2048
#define ACTN  2513
#define ACTP  2560
#define SB    (SEQ * BATCH)   // 8192

#define VMCNT0 asm volatile("s_waitcnt vmcnt(0)" ::: "memory")
#define BAR    __builtin_amdgcn_s_barrier()
#define SCHED0 __builtin_amdgcn_sched_barrier(0)
#define WAITV(n) asm volatile("s_waitcnt vmcnt(" #n ")" ::: "memory")

__device__ __forceinline__ unsigned short f2bf(float x) {
    unsigned u = __float_as_uint(x);
    u = u + 0x7FFFu + ((u >> 16) & 1u);
    return (unsigned short)(u >> 16);
}
__device__ __forceinline__ float bf2f(unsigned short h) {
    return __uint_as_float(((unsigned)h) << 16);
}
__device__ __forceinline__ float sigm(float x) { return 1.f / (1.f + __expf(-x)); }

__device__ __forceinline__ int gate_unperm(int nn) {
    return (((nn >> 4) & 3) << 10) | ((nn >> 6) << 4) | (nn & 15);
}

__device__ __forceinline__ void gload_lds16(const void* g, void* l) {
    __builtin_amdgcn_global_load_lds(
        (const __attribute__((address_space(1))) void*)g,
        (__attribute__((address_space(3))) void*)l,
        16, 0, 0);
}

// ---------------------------------------------------------------------------
// Generic C[M,N] = A[M,K]@W[N,K]^T (+bias), 128x128 tile, 2-phase dbuf,
// XOR-swizzled LDS (r7-proven). SWZ: 1-D grid, XCD-aware 8x8 super-tiles
// (requires (N/128)%8==0 || N/128==8-divisor handled by caller; M/128 %8==0).
// ---------------------------------------------------------------------------
template<bool OUT_BF16, bool HAS_BIAS, bool GUARD, bool SWZ>
__global__ __launch_bounds__(256)
void gemm_bt(const unsigned short* __restrict__ A,
             const unsigned short* __restrict__ W,
             void* __restrict__ Cv,
             const float* __restrict__ bias,
             int M, int N, int K, int ldc, int nvalid)
{
    __shared__ __align__(16) unsigned short sA[2][128 * 64];
    __shared__ __align__(16) unsigned short sB[2][128 * 64];

    int bxi, byi;
    if (SWZ) {
        // HW dispatches bid round-robin over 8 XCDs: xcd = bid & 7.
        // Give each XCD whole 8x8 super-tiles: L2 working set ~2MB A + 2MB W.
        const int bid = blockIdx.x;
        const int xcd = bid & 7;
        const int l   = bid >> 3;          // per-XCD sequence
        const int u   = l & 63;            // position within super-tile
        const int sl  = l >> 6;            // which super for this XCD
        const int s   = xcd + 8 * sl;      // global super-tile id
        const int nxs = (N >> 7) >> 3;     // supers along N (>=1)
        bxi = (s % nxs) * 8 + (u & 7);
        byi = (s / nxs) * 8 + (u >> 3);
    } else {
        bxi = blockIdx.x;
        byi = blockIdx.y;
    }

    const int t    = threadIdx.x;
    const int lane = t & 63;
    const int wave = t >> 6;
    const int m0   = byi * 128;
    const int n0   = bxi * 128;
    const int srow = t >> 3;                       // 0..31
    const int schk = t & 7;                        // linear LDS chunk
    const int swc  = (schk ^ (srow & 7)) * 8;      // swizzled global col (elems)
    const int sdst = srow * 64 + schk * 8;         // linear LDS dest (elems)
    const int wm   = (wave >> 1) * 64;
    const int wn   = (wave & 1) * 64;
    const int fl   = lane & 15;
    const int fk8  = (lane >> 4) * 8;              // 0 or 8
    const int l7   = lane & 7;                     // row&7 for fragment reads

    f32x4 acc[4][4] = {};

    const unsigned short* Abase = A + (size_t)(m0 + srow) * K + swc;
    const unsigned short* Wbase = W + (size_t)(n0 + srow) * K + swc;

    const int nkt = K >> 6;

#define G_STAGE(kt, buf)                                                     \
    {                                                                        \
        _Pragma("unroll")                                                    \
        for (int j = 0; j < 4; ++j) {                                        \
            gload_lds16(Abase + (size_t)j * 32 * K + (kt) * 64,              \
                        &sA[buf][sdst + j * 32 * 64]);                       \
            gload_lds16(Wbase + (size_t)j * 32 * K + (kt) * 64,              \
                        &sB[buf][sdst + j * 32 * 64]);                       \
        }                                                                    \
    }

    G_STAGE(0, 0);
    VMCNT0; BAR; SCHED0;

    int cur = 0;
    for (int kt = 0; kt < nkt; ++kt) {
        if (kt + 1 < nkt) G_STAGE(kt + 1, cur ^ 1);
        const unsigned short* sa = sA[cur];
        const unsigned short* sb = sB[cur];
#pragma unroll
        for (int kk = 0; kk < 64; kk += 32) {
            const int cs = (((kk + fk8) >> 3) ^ l7) * 8;  // swizzled read col
            short8 af[4], bfrag[4];
#pragma unroll
            for (int i = 0; i < 4; ++i)
                af[i] = *(const short8*)&sa[(wm + i * 16 + fl) * 64 + cs];
#pragma unroll
            for (int i = 0; i < 4; ++i)
                bfrag[i] = *(const short8*)&sb[(wn + i * 16 + fl) * 64 + cs];
#pragma unroll
            for (int mi = 0; mi < 4; ++mi)
#pragma unroll
                for (int ni = 0; ni < 4; ++ni)
                    acc[mi][ni] = __builtin_amdgcn_mfma_f32_16x16x32_bf16(
                        af[mi], bfrag[ni], acc[mi][ni], 0, 0, 0);
        }
        VMCNT0; BAR; SCHED0;
        cur ^= 1;
    }
#undef G_STAGE

    const int crb = (lane >> 4) * 4;
#pragma unroll
    for (int mi = 0; mi < 4; ++mi) {
#pragma unroll
        for (int ni = 0; ni < 4; ++ni) {
            const int col = n0 + wn + ni * 16 + fl;
            if (GUARD && col >= nvalid) continue;
            const float bv = HAS_BIAS ? bias[col] : 0.0f;
#pragma unroll
            for (int r = 0; r < 4; ++r) {
                const int row = m0 + wm + mi * 16 + crb + r;
                float v = acc[mi][ni][r] + bv;
                if (OUT_BF16)
                    ((unsigned short*)Cv)[(size_t)row * ldc + col] = f2bf(v);
                else
                    ((float*)Cv)[(size_t)row * ldc + col] = v;
            }
        }
    }
}

// ---------------------------------------------------------------------------
// Fused LSTM step: r10-verbatim (64x64 tile, grid (64,8), 256 thr, 2 blk/CU,
// 4 LDS buffers, depth-3 counted-vmcnt: WAITV(8) main, tail 4->0).
// ---------------------------------------------------------------------------
template<bool HAS_BIAS>
__global__ __launch_bounds__(256)
void lstm_step_fused(const unsigned short* __restrict__ hin,  // [512,1024] bf16
                     const unsigned short* __restrict__ W,    // [4096,1024] perm
                     const unsigned short* __restrict__ xg,   // [512,4096] perm
                     const float* __restrict__ bias,          // [4096] perm/null
                     float* __restrict__ c,                   // [512,1024] f32
                     unsigned short* __restrict__ hout)       // [512,1024] bf16
{
    __shared__ __align__(16) unsigned short sA[4][64 * 64];   // 32 KiB
    __shared__ __align__(16) unsigned short sB[4][64 * 64];   // 32 KiB

    const int t    = threadIdx.x;
    const int lane = t & 63;
    const int wave = t >> 6;          // 0..3, 16 rows each
    const int m0   = blockIdx.y * 64;
    const int n0   = blockIdx.x * 64;
    const int srow = t >> 3;          // 0..31
    const int schk = t & 7;
    const int swc  = (schk ^ (srow & 7)) * 8;
    const int sdst = srow * 64 + schk * 8;
    const int wm   = wave * 16;
    const int fl   = lane & 15;
    const int fk8  = (lane >> 4) * 8;
    const int l7   = lane & 7;

    f32x4 acc[4] = {};

    const unsigned short* Abase = hin + (size_t)(m0 + srow) * HID + swc;
    const unsigned short* Wbase = W + (size_t)(n0 + srow) * HID + swc;

#define S_STAGE(kt)                                                          \
    {                                                                        \
        const int _b = (kt) & 3;                                             \
        _Pragma("unroll")                                                    \
        for (int j = 0; j < 2; ++j) {                                        \
            gload_lds16(Abase + (size_t)j * 32 * HID + (kt) * 64,            \
                        &sA[_b][sdst + j * 32 * 64]);                        \
            gload_lds16(Wbase + (size_t)j * 32 * HID + (kt) * 64,            \
                        &sB[_b][sdst + j * 32 * 64]);                        \
        }                                                                    \
    }

#define S_COMP(kt)                                                           \
    {                                                                        \
        const unsigned short* sa = sA[(kt) & 3];                             \
        const unsigned short* sb = sB[(kt) & 3];                             \
        _Pragma("unroll")                                                    \
        for (int kk = 0; kk < 64; kk += 32) {                                \
            const int cs = (((kk + fk8) >> 3) ^ l7) * 8;                     \
            short8 af = *(const short8*)&sa[(wm + fl) * 64 + cs];            \
            _Pragma("unroll")                                                \
            for (int ni = 0; ni < 4; ++ni) {                                 \
                short8 bfr = *(const short8*)&sb[(ni * 16 + fl) * 64 + cs];  \
                acc[ni] = __builtin_amdgcn_mfma_f32_16x16x32_bf16(           \
                    af, bfr, acc[ni], 0, 0, 0);                              \
            }                                                                \
        }                                                                    \
    }

    S_STAGE(0); S_STAGE(1); S_STAGE(2);      // 12 loads in flight
    for (int kt = 0; kt < 14; ++kt) {
        WAITV(8); BAR; SCHED0;               // stage(kt) resident; 8 in flight
        if (kt + 3 < 16) S_STAGE(kt + 3);    // refill into buffer freed @kt-1
        S_COMP(kt);
    }
    WAITV(4); BAR; SCHED0; S_COMP(14);
    WAITV(0); BAR; SCHED0; S_COMP(15);
#undef S_STAGE
#undef S_COMP

    // fused cell epilogue: ni = gate (0:i 1:f 2:g 3:o), j = (n0>>6)*16 + fl
    const int crb = (lane >> 4) * 4;
    const int jj  = (n0 >> 6) * 16 + fl;
    float bv[4] = {0.f, 0.f, 0.f, 0.f};
    if (HAS_BIAS) {
#pragma unroll
        for (int ni = 0; ni < 4; ++ni) bv[ni] = bias[n0 + ni * 16 + fl];
    }
#pragma unroll
    for (int r = 0; r < 4; ++r) {
        const int b = m0 + wm + crb + r;
        float v[4];
#pragma unroll
        for (int ni = 0; ni < 4; ++ni)
            v[ni] = acc[ni][r] + bv[ni] + bf2f(xg[(size_t)b * GATE4 + n0 + ni * 16 + fl]);
        const int ci = b * HID + jj;
        float cv = sigm(v[1]) * c[ci] + sigm(v[0]) * tanhf(v[2]);
        c[ci] = cv;
        hout[ci] = f2bf(sigm(v[3]) * tanhf(cv));
    }
}

// ---------------------------------------------------------------------------
// Step 0 of rolling LSTM (h=0, c=0): pure cell on xg_r[0] + bhh
// ---------------------------------------------------------------------------
__global__ void lstm_cell0_k(const unsigned short* __restrict__ xg,
                             const float* __restrict__ bias,
                             float* __restrict__ c, unsigned short* __restrict__ h)
{
    int idx = blockIdx.x * blockDim.x + threadIdx.x;  // < 512*1024
    int b = idx >> 10, j = idx & 1023;
    int base = (j & 15) | ((j >> 4) << 6);
    float v[4];
#pragma unroll
    for (int g = 0; g < 4; ++g) {
        int col = base | (g << 4);
        v[g] = bf2f(xg[(size_t)b * GATE4 + col]) + bias[col];
    }
    float cv = sigm(v[0]) * tanhf(v[2]);   // c_prev = 0
    c[idx] = cv;
    h[idx] = f2bf(sigm(v[3]) * tanhf(cv));
}

// ---------------------------------------------------------------------------
// One merged prep kernel (all conversions/permutations/folds)
// ---------------------------------------------------------------------------
#define PB_IN   16384
#define PB_W1   (PB_IN + 2048)       // 18432
#define PB_WR   (PB_W1 + 4096)       // 22528
#define PB_WU   (PB_WR + 4096)       // 26624
#define PB_WHR  (PB_WU + 4096)       // 30720
#define PB_WHU  (PB_WHR + 4096)      // 34816
#define PB_WC   (PB_WHU + 2560)      // 37376
#define PB_END  (PB_WC + 26)         // 37402

__device__ __forceinline__ void cvt4(const float* src, unsigned short* dst) {
    float4 v = *(const float4*)src;
    ushort4 o;
    o.x = f2bf(v.x); o.y = f2bf(v.y); o.z = f2bf(v.z); o.w = f2bf(v.w);
    *(ushort4*)dst = o;
}

__global__ void prep_all_k(const float* __restrict__ inputs, const float* __restrict__ W1,
                           const float* __restrict__ Wih_r, const float* __restrict__ Wih_u,
                           const float* __restrict__ Whh_r, const float* __restrict__ Whh_u,
                           const float* __restrict__ Wc,
                           const float* __restrict__ bih_r, const float* __restrict__ bhh_r,
                           const float* __restrict__ bih_u, const float* __restrict__ bhh_u,
                           const float* __restrict__ bc,
                           unsigned short* __restrict__ in_bf, unsigned short* __restrict__ W1b,
                           unsigned short* __restrict__ Wrb, unsigned short* __restrict__ Wub,
                           unsigned short* __restrict__ Whhrb, unsigned short* __restrict__ Whhub,
                           unsigned short* __restrict__ Wcb,
                           float* __restrict__ bihr_p, float* __restrict__ bhhr_p,
                           float* __restrict__ bu_p, float* __restrict__ bc_p)
{
    const int blk = blockIdx.x, tid = threadIdx.x;
    if (blk < PB_IN) {                       // inputs f32 -> bf16 (8192x2048)
        int i = blk * 256 + tid;
        cvt4(inputs + (size_t)i * 4, in_bf + (size_t)i * 4);
    } else if (blk < PB_W1) {                // W1 f32 -> bf16 (1024x2048)
        int i = (blk - PB_IN) * 256 + tid;
        cvt4(W1 + (size_t)i * 4, W1b + (size_t)i * 4);
    } else if (blk < PB_WR) {                // Wih_r: sum halves + perm
        int i = (blk - PB_W1) * 256 + tid;
        int nn = i >> 8, k4 = (i & 255) * 4;
        const float* row = Wih_r + (size_t)gate_unperm(nn) * FEAT;
        float4 a = *(const float4*)(row + k4);
        float4 b = *(const float4*)(row + HID + k4);
        ushort4 o;
        o.x = f2bf(a.x + b.x); o.y = f2bf(a.y + b.y);
        o.z = f2bf(a.z + b.z); o.w = f2bf(a.w + b.w);
        *(ushort4*)(Wrb + (size_t)nn * HID + k4) = o;
    } else if (blk < PB_WU) {                // Wih_u: sum halves + perm
        int i = (blk - PB_WR) * 256 + tid;
        int nn = i >> 8, k4 = (i & 255) * 4;
        const float* row = Wih_u + (size_t)gate_unperm(nn) * FEAT;
        float4 a = *(const float4*)(row + k4);
        float4 b = *(const float4*)(row + HID + k4);
        ushort4 o;
        o.x = f2bf(a.x + b.x); o.y = f2bf(a.y + b.y);
        o.z = f2bf(a.z + b.z); o.w = f2bf(a.w + b.w);
        *(ushort4*)(Wub + (size_t)nn * HID + k4) = o;
    } else if (blk < PB_WHR) {               // Whh_r perm
        int i = (blk - PB_WU) * 256 + tid;
        int nn = i >> 8, k4 = (i & 255) * 4;
        cvt4(Whh_r + (size_t)gate_unperm(nn) * HID + k4, Whhrb + (size_t)nn * HID + k4);
    } else if (blk < PB_WHU) {               // Whh_u perm
        int i = (blk - PB_WHR) * 256 + tid;
        int nn = i >> 8, k4 = (i & 255) * 4;
        cvt4(Whh_u + (size_t)gate_unperm(nn) * HID + k4, Whhub + (size_t)nn * HID + k4);
    } else if (blk < PB_WC) {                // Wc pad to 2560 rows
        int i = (blk - PB_WHU) * 256 + tid;
        int g = i >> 8, k4 = (i & 255) * 4;
        if (g < ACTN) {
            cvt4(Wc + (size_t)g * HID + k4, Wcb + (size_t)g * HID + k4);
        } else {
            ushort4 o; o.x = o.y = o.z = o.w = 0;
            *(ushort4*)(Wcb + (size_t)g * HID + k4) = o;
        }
    } else {                                 // biases (4096 perm + 2560 bc)
        int i = (blk - PB_WC) * 256 + tid;
        if (i < GATE4) {
            int src = gate_unperm(i);
            bihr_p[i] = bih_r[src];
            bhhr_p[i] = bhh_r[src];
            bu_p[i]   = bih_u[src] + bhh_u[src];
        } else if (i < GATE4 + ACTP) {
            int j = i - GATE4;
            bc_p[j] = (j < ACTN) ? bc[j] : 0.f;
        }
    }
}

// ---------------------------------------------------------------------------
// Workspace layout (bytes) — end 162,588,672 (proven footprint)
// ---------------------------------------------------------------------------
#define OFF_IN_BF 0ull
#define OFF_X_BF  33554432ull
#define OFF_XGR   50331648ull
#define OFF_W1    117440512ull
#define OFF_WR    121634816ull
#define OFF_WHHR  130023424ull
#define OFF_WU    138412032ull
#define OFF_WHHU  146800640ull
#define OFF_WCB   155189248ull      // 2560*1024*2 -> ends 160432128
#define OFF_H0    160432128ull      // 1 MiB
#define OFF_H1    161480704ull      // 1 MiB
#define OFF_BC    162529280ull
#define OFF_BU    162539520ull
#define OFF_BIHR  162555904ull
#define OFF_BHHR  162572288ull
// xg_u (4 MiB) and c_buf (2 MiB) overlay in_bf (dead after G1).

extern "C" void kernel_launch(void* const* d_in, const int* in_sizes, int n_in,
                              void* d_out, int out_size, void* d_ws, size_t ws_size,
                              hipStream_t stream)
{
    const float* inputs = (const float*)d_in[0];
    const float* W1     = (const float*)d_in[1];
    const float* b1     = (const float*)d_in[2];
    const float* Wih_r  = (const float*)d_in[3];
    const float* Whh_r  = (const float*)d_in[4];
    const float* bih_r  = (const float*)d_in[5];
    const float* bhh_r  = (const float*)d_in[6];
    const float* Wih_u  = (const float*)d_in[7];
    const float* Whh_u  = (const float*)d_in[8];
    const float* bih_u  = (const float*)d_in[9];
    const float* bhh_u  = (const float*)d_in[10];
    const float* Wc     = (const float*)d_in[11];
    const float* bc     = (const float*)d_in[12];
    float* out = (float*)d_out;
    char* ws = (char*)d_ws;

    unsigned short* in_bf = (unsigned short*)(ws + OFF_IN_BF);
    unsigned short* x_bf  = (unsigned short*)(ws + OFF_X_BF);
    unsigned short* xg_r  = (unsigned short*)(ws + OFF_XGR);
    unsigned short* W1b   = (unsigned short*)(ws + OFF_W1);
    unsigned short* Wrb   = (unsigned short*)(ws + OFF_WR);
    unsigned short* Whhrb = (unsigned short*)(ws + OFF_WHHR);
    unsigned short* Wub   = (unsigned short*)(ws + OFF_WU);
    unsigned short* Whhub = (unsigned short*)(ws + OFF_WHHU);
    unsigned short* Wcb   = (unsigned short*)(ws + OFF_WCB);
    unsigned short* h0    = (unsigned short*)(ws + OFF_H0);
    unsigned short* h1    = (unsigned short*)(ws + OFF_H1);
    float*          bc_p  = (float*)(ws + OFF_BC);
    float*          bu_p  = (float*)(ws + OFF_BU);
    float*          bihr_p= (float*)(ws + OFF_BIHR);
    float*          bhhr_p= (float*)(ws + OFF_BHHR);
    unsigned short* xg_u  = (unsigned short*)(ws + OFF_IN_BF);           // 4 MiB
    float*          c_buf = (float*)(ws + OFF_IN_BF + 4194304ull);      // 2 MiB

    const dim3 blk(256);

    // ---- prep (one launch) ----
    prep_all_k<<<dim3(PB_END), blk, 0, stream>>>(
        inputs, W1, Wih_r, Wih_u, Whh_r, Whh_u, Wc,
        bih_r, bhh_r, bih_u, bhh_u, bc,
        in_bf, W1b, Wrb, Wub, Whhrb, Whhub, Wcb,
        bihr_p, bhhr_p, bu_p, bc_p);

    // ---- G1: x = inputs @ W1^T + b1 -> bf16 [8192,1024]  (XCD-swizzled) ----
    gemm_bt<true, true, false, true><<<dim3((HID / 128) * (SB / 128)), blk, 0, stream>>>(
        in_bf, W1b, x_bf, b1, SB, HID, FEAT, HID, HID);

    // ---- G2: xg_r = x @ Wr_eff^T + bih_r -> bf16 [8192,4096] (XCD-swizzled) ----
    gemm_bt<true, true, false, true><<<dim3((GATE4 / 128) * (SB / 128)), blk, 0, stream>>>(
        x_bf, Wrb, xg_r, bihr_p, SB, GATE4, HID, GATE4, GATE4);

    // ---- xg_u = x[15] @ Wu_eff^T + (bih_u + bhh_u) -> bf16 [512,4096] ----
    gemm_bt<true, true, false, false><<<dim3(GATE4 / 128, BATCH / 128), blk, 0, stream>>>(
        x_bf + (size_t)(SEQ - 1) * BATCH * HID, Wub, xg_u, bu_p,
        BATCH, GATE4, HID, GATE4, GATE4);

    // ---- rolling LSTM: step 0 pure cell (h=c=0), then 15 fused steps ----
    lstm_cell0_k<<<dim3(BATCH * HID / 256), blk, 0, stream>>>(xg_r, bhhr_p, c_buf, h0);
    unsigned short* hc = h0;
    unsigned short* hn = h1;
    for (int s = 1; s < SEQ; ++s) {
        lstm_step_fused<true><<<dim3(GATE4 / 64, BATCH / 64), blk, 0, stream>>>(
            hc, Whhrb, xg_r + (size_t)s * BATCH * GATE4, bhhr_p, c_buf, hn);
        unsigned short* tmp = hc; hc = hn; hn = tmp;
    }

    // ---- 2 unroll steps (bias folded into xg_u) ----
    for (int s = 0; s < 2; ++s) {
        lstm_step_fused<false><<<dim3(GATE4 / 64, BATCH / 64), blk, 0, stream>>>(
            hc, Whhub, xg_u, nullptr, c_buf, hn);
        unsigned short* tmp = hc; hc = hn; hn = tmp;
    }

    // ---- classifier: y = h @ Wc^T + bc -> fp32 [512,2513] ----
    gemm_bt<false, true, true, false><<<dim3(ACTP / 128, BATCH / 128), blk, 0, stream>>>(
        hc, Wcb, out, bc_p, BATCH, ACTP, HID, ACTN, ACTN);
}

// Round 14
// 441.244 us; speedup vs baseline: 1.0916x; 1.0024x over previous
//
#include <hip/hip_runtime.h>
#include <stdint.h>

// ---------------------------------------------------------------------------
// RULSTM collapsed: y = h2 @ Wc.T + bc, h2 = 2 unroll steps from rolling-LSTM
// final state. Gate axis permuted (n_new=(j&15)|gate<<4|(j>>4)<<6) so the LSTM
// cell fuses into the GEMM epilogue.
// r14: base = r13 (best, 442us). Two independent changes:
//  (1) gemm_bt K-loop: 2-buf COUNTED vmcnt (WAITV(8) top; BAR; COMP; BAR;
//      STAGE(kt+2)) -- removes the per-chunk vmcnt(0) drain while keeping
//      2 blocks/CU. Last iter peeled with VMCNT0. Same swizzle/K-order.
//  (2) step kernel: T5 s_setprio(1/0) around the per-chunk compute cluster
//      (counted-vmcnt schedule has the role-split T5 needs; gemm left alone).
// ---------------------------------------------------------------------------

typedef __attribute__((ext_vector_type(8))) short short8;
typedef __attribute__((ext_vector_type(4))) float f32x4;

#define SEQ   16
#define BATCH 512
#define HID   1024
#define GATE4 4096
#define FEAT  2048
#define ACTN  2513
#define ACTP  2560
#define SB    (SEQ * BATCH)   // 8192

#define VMCNT0 asm volatile("s_waitcnt vmcnt(0)" ::: "memory")
#define BAR    __builtin_amdgcn_s_barrier()
#define SCHED0 __builtin_amdgcn_sched_barrier(0)
#define WAITV(n) asm volatile("s_waitcnt vmcnt(" #n ")" ::: "memory")

__device__ __forceinline__ unsigned short f2bf(float x) {
    unsigned u = __float_as_uint(x);
    u = u + 0x7FFFu + ((u >> 16) & 1u);
    return (unsigned short)(u >> 16);
}
__device__ __forceinline__ float bf2f(unsigned short h) {
    return __uint_as_float(((unsigned)h) << 16);
}
__device__ __forceinline__ float sigm(float x) { return 1.f / (1.f + __expf(-x)); }

__device__ __forceinline__ int gate_unperm(int nn) {
    return (((nn >> 4) & 3) << 10) | ((nn >> 6) << 4) | (nn & 15);
}

__device__ __forceinline__ void gload_lds16(const void* g, void* l) {
    __builtin_amdgcn_global_load_lds(
        (const __attribute__((address_space(1))) void*)g,
        (__attribute__((address_space(3))) void*)l,
        16, 0, 0);
}

// ---------------------------------------------------------------------------
// Generic C[M,N] = A[M,K]@W[N,K]^T (+bias), 128x128 tile, 2-buf counted-vmcnt
// pipeline (no drain in main loop), XOR-swizzled LDS (r7-proven formulas),
// optional XCD-aware 8x8 super-tile block swizzle (r13-proven).
// ---------------------------------------------------------------------------
template<bool OUT_BF16, bool HAS_BIAS, bool GUARD, bool SWZ>
__global__ __launch_bounds__(256)
void gemm_bt(const unsigned short* __restrict__ A,
             const unsigned short* __restrict__ W,
             void* __restrict__ Cv,
             const float* __restrict__ bias,
             int M, int N, int K, int ldc, int nvalid)
{
    __shared__ __align__(16) unsigned short sA[2][128 * 64];
    __shared__ __align__(16) unsigned short sB[2][128 * 64];

    int bxi, byi;
    if (SWZ) {
        const int bid = blockIdx.x;
        const int xcd = bid & 7;
        const int l   = bid >> 3;
        const int u   = l & 63;
        const int sl  = l >> 6;
        const int s   = xcd + 8 * sl;
        const int nxs = (N >> 7) >> 3;
        bxi = (s % nxs) * 8 + (u & 7);
        byi = (s / nxs) * 8 + (u >> 3);
    } else {
        bxi = blockIdx.x;
        byi = blockIdx.y;
    }

    const int t    = threadIdx.x;
    const int lane = t & 63;
    const int wave = t >> 6;
    const int m0   = byi * 128;
    const int n0   = bxi * 128;
    const int srow = t >> 3;                       // 0..31
    const int schk = t & 7;                        // linear LDS chunk
    const int swc  = (schk ^ (srow & 7)) * 8;      // swizzled global col (elems)
    const int sdst = srow * 64 + schk * 8;         // linear LDS dest (elems)
    const int wm   = (wave >> 1) * 64;
    const int wn   = (wave & 1) * 64;
    const int fl   = lane & 15;
    const int fk8  = (lane >> 4) * 8;              // 0 or 8
    const int l7   = lane & 7;                     // row&7 for fragment reads

    f32x4 acc[4][4] = {};

    const unsigned short* Abase = A + (size_t)(m0 + srow) * K + swc;
    const unsigned short* Wbase = W + (size_t)(n0 + srow) * K + swc;

    const int nkt = K >> 6;

#define G_STAGE(kt)                                                          \
    {                                                                        \
        const int _b = (kt) & 1;                                             \
        _Pragma("unroll")                                                    \
        for (int j = 0; j < 4; ++j) {                                        \
            gload_lds16(Abase + (size_t)j * 32 * K + (kt) * 64,              \
                        &sA[_b][sdst + j * 32 * 64]);                        \
            gload_lds16(Wbase + (size_t)j * 32 * K + (kt) * 64,              \
                        &sB[_b][sdst + j * 32 * 64]);                        \
        }                                                                    \
    }

#define G_COMP(kt)                                                           \
    {                                                                        \
        const unsigned short* sa = sA[(kt) & 1];                             \
        const unsigned short* sb = sB[(kt) & 1];                             \
        _Pragma("unroll")                                                    \
        for (int kk = 0; kk < 64; kk += 32) {                                \
            const int cs = (((kk + fk8) >> 3) ^ l7) * 8;                     \
            short8 af[4], bfrag[4];                                          \
            _Pragma("unroll")                                                \
            for (int i = 0; i < 4; ++i)                                      \
                af[i] = *(const short8*)&sa[(wm + i * 16 + fl) * 64 + cs];   \
            _Pragma("unroll")                                                \
            for (int i = 0; i < 4; ++i)                                      \
                bfrag[i] = *(const short8*)&sb[(wn + i * 16 + fl) * 64 + cs];\
            _Pragma("unroll")                                                \
            for (int mi = 0; mi < 4; ++mi)                                   \
                _Pragma("unroll")                                            \
                for (int ni = 0; ni < 4; ++ni)                               \
                    acc[mi][ni] = __builtin_amdgcn_mfma_f32_16x16x32_bf16(   \
                        af[mi], bfrag[ni], acc[mi][ni], 0, 0, 0);            \
        }                                                                    \
    }

    // prologue: two chunks in flight (16 loads/wave)
    G_STAGE(0);
    G_STAGE(1);

    // main loop: counted wait (own chunk only), no drain
    for (int kt = 0; kt < nkt - 1; ++kt) {
        WAITV(8); BAR; SCHED0;           // stage(kt) resident; stage(kt+1) flying
        G_COMP(kt);
        BAR;                             // all waves done reading buf (kt&1)
        if (kt + 2 < nkt) G_STAGE(kt + 2);
    }
    // last chunk: full drain
    VMCNT0; BAR; SCHED0;
    G_COMP(nkt - 1);
#undef G_STAGE
#undef G_COMP

    const int crb = (lane >> 4) * 4;
#pragma unroll
    for (int mi = 0; mi < 4; ++mi) {
#pragma unroll
        for (int ni = 0; ni < 4; ++ni) {
            const int col = n0 + wn + ni * 16 + fl;
            if (GUARD && col >= nvalid) continue;
            const float bv = HAS_BIAS ? bias[col] : 0.0f;
#pragma unroll
            for (int r = 0; r < 4; ++r) {
                const int row = m0 + wm + mi * 16 + crb + r;
                float v = acc[mi][ni][r] + bv;
                if (OUT_BF16)
                    ((unsigned short*)Cv)[(size_t)row * ldc + col] = f2bf(v);
                else
                    ((float*)Cv)[(size_t)row * ldc + col] = v;
            }
        }
    }
}

// ---------------------------------------------------------------------------
// Fused LSTM step: r10-verbatim schedule (64x64 tile, grid (64,8), 256 thr,
// 2 blk/CU, 4 LDS buffers, depth-3 counted-vmcnt) + T5 setprio around the
// per-chunk compute cluster.
// ---------------------------------------------------------------------------
template<bool HAS_BIAS>
__global__ __launch_bounds__(256)
void lstm_step_fused(const unsigned short* __restrict__ hin,  // [512,1024] bf16
                     const unsigned short* __restrict__ W,    // [4096,1024] perm
                     const unsigned short* __restrict__ xg,   // [512,4096] perm
                     const float* __restrict__ bias,          // [4096] perm/null
                     float* __restrict__ c,                   // [512,1024] f32
                     unsigned short* __restrict__ hout)       // [512,1024] bf16
{
    __shared__ __align__(16) unsigned short sA[4][64 * 64];   // 32 KiB
    __shared__ __align__(16) unsigned short sB[4][64 * 64];   // 32 KiB

    const int t    = threadIdx.x;
    const int lane = t & 63;
    const int wave = t >> 6;          // 0..3, 16 rows each
    const int m0   = blockIdx.y * 64;
    const int n0   = blockIdx.x * 64;
    const int srow = t >> 3;          // 0..31
    const int schk = t & 7;
    const int swc  = (schk ^ (srow & 7)) * 8;
    const int sdst = srow * 64 + schk * 8;
    const int wm   = wave * 16;
    const int fl   = lane & 15;
    const int fk8  = (lane >> 4) * 8;
    const int l7   = lane & 7;

    f32x4 acc[4] = {};

    const unsigned short* Abase = hin + (size_t)(m0 + srow) * HID + swc;
    const unsigned short* Wbase = W + (size_t)(n0 + srow) * HID + swc;

#define S_STAGE(kt)                                                          \
    {                                                                        \
        const int _b = (kt) & 3;                                             \
        _Pragma("unroll")                                                    \
        for (int j = 0; j < 2; ++j) {                                        \
            gload_lds16(Abase + (size_t)j * 32 * HID + (kt) * 64,            \
                        &sA[_b][sdst + j * 32 * 64]);                        \
            gload_lds16(Wbase + (size_t)j * 32 * HID + (kt) * 64,            \
                        &sB[_b][sdst + j * 32 * 64]);                        \
        }                                                                    \
    }

#define S_COMP(kt)                                                           \
    {                                                                        \
        const unsigned short* sa = sA[(kt) & 3];                             \
        const unsigned short* sb = sB[(kt) & 3];                             \
        __builtin_amdgcn_s_setprio(1);                                       \
        _Pragma("unroll")                                                    \
        for (int kk = 0; kk < 64; kk += 32) {                                \
            const int cs = (((kk + fk8) >> 3) ^ l7) * 8;                     \
            short8 af = *(const short8*)&sa[(wm + fl) * 64 + cs];            \
            _Pragma("unroll")                                                \
            for (int ni = 0; ni < 4; ++ni) {                                 \
                short8 bfr = *(const short8*)&sb[(ni * 16 + fl) * 64 + cs];  \
                acc[ni] = __builtin_amdgcn_mfma_f32_16x16x32_bf16(           \
                    af, bfr, acc[ni], 0, 0, 0);                              \
            }                                                                \
        }                                                                    \
        __builtin_amdgcn_s_setprio(0);                                       \
    }

    S_STAGE(0); S_STAGE(1); S_STAGE(2);      // 12 loads in flight
    for (int kt = 0; kt < 14; ++kt) {
        WAITV(8); BAR; SCHED0;               // stage(kt) resident; 8 in flight
        if (kt + 3 < 16) S_STAGE(kt + 3);    // refill into buffer freed @kt-1
        S_COMP(kt);
    }
    WAITV(4); BAR; SCHED0; S_COMP(14);
    WAITV(0); BAR; SCHED0; S_COMP(15);
#undef S_STAGE
#undef S_COMP

    // fused cell epilogue: ni = gate (0:i 1:f 2:g 3:o), j = (n0>>6)*16 + fl
    const int crb = (lane >> 4) * 4;
    const int jj  = (n0 >> 6) * 16 + fl;
    float bv[4] = {0.f, 0.f, 0.f, 0.f};
    if (HAS_BIAS) {
#pragma unroll
        for (int ni = 0; ni < 4; ++ni) bv[ni] = bias[n0 + ni * 16 + fl];
    }
#pragma unroll
    for (int r = 0; r < 4; ++r) {
        const int b = m0 + wm + crb + r;
        float v[4];
#pragma unroll
        for (int ni = 0; ni < 4; ++ni)
            v[ni] = acc[ni][r] + bv[ni] + bf2f(xg[(size_t)b * GATE4 + n0 + ni * 16 + fl]);
        const int ci = b * HID + jj;
        float cv = sigm(v[1]) * c[ci] + sigm(v[0]) * tanhf(v[2]);
        c[ci] = cv;
        hout[ci] = f2bf(sigm(v[3]) * tanhf(cv));
    }
}

// ---------------------------------------------------------------------------
// Step 0 of rolling LSTM (h=0, c=0): pure cell on xg_r[0] + bhh
// ---------------------------------------------------------------------------
__global__ void lstm_cell0_k(const unsigned short* __restrict__ xg,
                             const float* __restrict__ bias,
                             float* __restrict__ c, unsigned short* __restrict__ h)
{
    int idx = blockIdx.x * blockDim.x + threadIdx.x;  // < 512*1024
    int b = idx >> 10, j = idx & 1023;
    int base = (j & 15) | ((j >> 4) << 6);
    float v[4];
#pragma unroll
    for (int g = 0; g < 4; ++g) {
        int col = base | (g << 4);
        v[g] = bf2f(xg[(size_t)b * GATE4 + col]) + bias[col];
    }
    float cv = sigm(v[0]) * tanhf(v[2]);   // c_prev = 0
    c[idx] = cv;
    h[idx] = f2bf(sigm(v[3]) * tanhf(cv));
}

// ---------------------------------------------------------------------------
// One merged prep kernel (all conversions/permutations/folds)
// ---------------------------------------------------------------------------
#define PB_IN   16384
#define PB_W1   (PB_IN + 2048)       // 18432
#define PB_WR   (PB_W1 + 4096)       // 22528
#define PB_WU   (PB_WR + 4096)       // 26624
#define PB_WHR  (PB_WU + 4096)       // 30720
#define PB_WHU  (PB_WHR + 4096)      // 34816
#define PB_WC   (PB_WHU + 2560)      // 37376
#define PB_END  (PB_WC + 26)         // 37402

__device__ __forceinline__ void cvt4(const float* src, unsigned short* dst) {
    float4 v = *(const float4*)src;
    ushort4 o;
    o.x = f2bf(v.x); o.y = f2bf(v.y); o.z = f2bf(v.z); o.w = f2bf(v.w);
    *(ushort4*)dst = o;
}

__global__ void prep_all_k(const float* __restrict__ inputs, const float* __restrict__ W1,
                           const float* __restrict__ Wih_r, const float* __restrict__ Wih_u,
                           const float* __restrict__ Whh_r, const float* __restrict__ Whh_u,
                           const float* __restrict__ Wc,
                           const float* __restrict__ bih_r, const float* __restrict__ bhh_r,
                           const float* __restrict__ bih_u, const float* __restrict__ bhh_u,
                           const float* __restrict__ bc,
                           unsigned short* __restrict__ in_bf, unsigned short* __restrict__ W1b,
                           unsigned short* __restrict__ Wrb, unsigned short* __restrict__ Wub,
                           unsigned short* __restrict__ Whhrb, unsigned short* __restrict__ Whhub,
                           unsigned short* __restrict__ Wcb,
                           float* __restrict__ bihr_p, float* __restrict__ bhhr_p,
                           float* __restrict__ bu_p, float* __restrict__ bc_p)
{
    const int blk = blockIdx.x, tid = threadIdx.x;
    if (blk < PB_IN) {                       // inputs f32 -> bf16 (8192x2048)
        int i = blk * 256 + tid;
        cvt4(inputs + (size_t)i * 4, in_bf + (size_t)i * 4);
    } else if (blk < PB_W1) {                // W1 f32 -> bf16 (1024x2048)
        int i = (blk - PB_IN) * 256 + tid;
        cvt4(W1 + (size_t)i * 4, W1b + (size_t)i * 4);
    } else if (blk < PB_WR) {                // Wih_r: sum halves + perm
        int i = (blk - PB_W1) * 256 + tid;
        int nn = i >> 8, k4 = (i & 255) * 4;
        const float* row = Wih_r + (size_t)gate_unperm(nn) * FEAT;
        float4 a = *(const float4*)(row + k4);
        float4 b = *(const float4*)(row + HID + k4);
        ushort4 o;
        o.x = f2bf(a.x + b.x); o.y = f2bf(a.y + b.y);
        o.z = f2bf(a.z + b.z); o.w = f2bf(a.w + b.w);
        *(ushort4*)(Wrb + (size_t)nn * HID + k4) = o;
    } else if (blk < PB_WU) {                // Wih_u: sum halves + perm
        int i = (blk - PB_WR) * 256 + tid;
        int nn = i >> 8, k4 = (i & 255) * 4;
        const float* row = Wih_u + (size_t)gate_unperm(nn) * FEAT;
        float4 a = *(const float4*)(row + k4);
        float4 b = *(const float4*)(row + HID + k4);
        ushort4 o;
        o.x = f2bf(a.x + b.x); o.y = f2bf(a.y + b.y);
        o.z = f2bf(a.z + b.z); o.w = f2bf(a.w + b.w);
        *(ushort4*)(Wub + (size_t)nn * HID + k4) = o;
    } else if (blk < PB_WHR) {               // Whh_r perm
        int i = (blk - PB_WU) * 256 + tid;
        int nn = i >> 8, k4 = (i & 255) * 4;
        cvt4(Whh_r + (size_t)gate_unperm(nn) * HID + k4, Whhrb + (size_t)nn * HID + k4);
    } else if (blk < PB_WHU) {               // Whh_u perm
        int i = (blk - PB_WHR) * 256 + tid;
        int nn = i >> 8, k4 = (i & 255) * 4;
        cvt4(Whh_u + (size_t)gate_unperm(nn) * HID + k4, Whhub + (size_t)nn * HID + k4);
    } else if (blk < PB_WC) {                // Wc pad to 2560 rows
        int i = (blk - PB_WHU) * 256 + tid;
        int g = i >> 8, k4 = (i & 255) * 4;
        if (g < ACTN) {
            cvt4(Wc + (size_t)g * HID + k4, Wcb + (size_t)g * HID + k4);
        } else {
            ushort4 o; o.x = o.y = o.z = o.w = 0;
            *(ushort4*)(Wcb + (size_t)g * HID + k4) = o;
        }
    } else {                                 // biases (4096 perm + 2560 bc)
        int i = (blk - PB_WC) * 256 + tid;
        if (i < GATE4) {
            int src = gate_unperm(i);
            bihr_p[i] = bih_r[src];
            bhhr_p[i] = bhh_r[src];
            bu_p[i]   = bih_u[src] + bhh_u[src];
        } else if (i < GATE4 + ACTP) {
            int j = i - GATE4;
            bc_p[j] = (j < ACTN) ? bc[j] : 0.f;
        }
    }
}

// ---------------------------------------------------------------------------
// Workspace layout (bytes) — end 162,588,672 (proven footprint)
// ---------------------------------------------------------------------------
#define OFF_IN_BF 0ull
#define OFF_X_BF  33554432ull
#define OFF_XGR   50331648ull
#define OFF_W1    117440512ull
#define OFF_WR    121634816ull
#define OFF_WHHR  130023424ull
#define OFF_WU    138412032ull
#define OFF_WHHU  146800640ull
#define OFF_WCB   155189248ull      // 2560*1024*2 -> ends 160432128
#define OFF_H0    160432128ull      // 1 MiB
#define OFF_H1    161480704ull      // 1 MiB
#define OFF_BC    162529280ull
#define OFF_BU    162539520ull
#define OFF_BIHR  162555904ull
#define OFF_BHHR  162572288ull
// xg_u (4 MiB) and c_buf (2 MiB) overlay in_bf (dead after G1).

extern "C" void kernel_launch(void* const* d_in, const int* in_sizes, int n_in,
                              void* d_out, int out_size, void* d_ws, size_t ws_size,
                              hipStream_t stream)
{
    const float* inputs = (const float*)d_in[0];
    const float* W1     = (const float*)d_in[1];
    const float* b1     = (const float*)d_in[2];
    const float* Wih_r  = (const float*)d_in[3];
    const float* Whh_r  = (const float*)d_in[4];
    const float* bih_r  = (const float*)d_in[5];
    const float* bhh_r  = (const float*)d_in[6];
    const float* Wih_u  = (const float*)d_in[7];
    const float* Whh_u  = (const float*)d_in[8];
    const float* bih_u  = (const float*)d_in[9];
    const float* bhh_u  = (const float*)d_in[10];
    const float* Wc     = (const float*)d_in[11];
    const float* bc     = (const float*)d_in[12];
    float* out = (float*)d_out;
    char* ws = (char*)d_ws;

    unsigned short* in_bf = (unsigned short*)(ws + OFF_IN_BF);
    unsigned short* x_bf  = (unsigned short*)(ws + OFF_X_BF);
    unsigned short* xg_r  = (unsigned short*)(ws + OFF_XGR);
    unsigned short* W1b   = (unsigned short*)(ws + OFF_W1);
    unsigned short* Wrb   = (unsigned short*)(ws + OFF_WR);
    unsigned short* Whhrb = (unsigned short*)(ws + OFF_WHHR);
    unsigned short* Wub   = (unsigned short*)(ws + OFF_WU);
    unsigned short* Whhub = (unsigned short*)(ws + OFF_WHHU);
    unsigned short* Wcb   = (unsigned short*)(ws + OFF_WCB);
    unsigned short* h0    = (unsigned short*)(ws + OFF_H0);
    unsigned short* h1    = (unsigned short*)(ws + OFF_H1);
    float*          bc_p  = (float*)(ws + OFF_BC);
    float*          bu_p  = (float*)(ws + OFF_BU);
    float*          bihr_p= (float*)(ws + OFF_BIHR);
    float*          bhhr_p= (float*)(ws + OFF_BHHR);
    unsigned short* xg_u  = (unsigned short*)(ws + OFF_IN_BF);           // 4 MiB
    float*          c_buf = (float*)(ws + OFF_IN_BF + 4194304ull);      // 2 MiB

    const dim3 blk(256);

    // ---- prep (one launch) ----
    prep_all_k<<<dim3(PB_END), blk, 0, stream>>>(
        inputs, W1, Wih_r, Wih_u, Whh_r, Whh_u, Wc,
        bih_r, bhh_r, bih_u, bhh_u, bc,
        in_bf, W1b, Wrb, Wub, Whhrb, Whhub, Wcb,
        bihr_p, bhhr_p, bu_p, bc_p);

    // ---- G1: x = inputs @ W1^T + b1 -> bf16 [8192,1024]  (XCD-swizzled) ----
    gemm_bt<true, true, false, true><<<dim3((HID / 128) * (SB / 128)), blk, 0, stream>>>(
        in_bf, W1b, x_bf, b1, SB, HID, FEAT, HID, HID);

    // ---- G2: xg_r = x @ Wr_eff^T + bih_r -> bf16 [8192,4096] (XCD-swizzled) ----
    gemm_bt<true, true, false, true><<<dim3((GATE4 / 128) * (SB / 128)), blk, 0, stream>>>(
        x_bf, Wrb, xg_r, bihr_p, SB, GATE4, HID, GATE4, GATE4);

    // ---- xg_u = x[15] @ Wu_eff^T + (bih_u + bhh_u) -> bf16 [512,4096] ----
    gemm_bt<true, true, false, false><<<dim3(GATE4 / 128, BATCH / 128), blk, 0, stream>>>(
        x_bf + (size_t)(SEQ - 1) * BATCH * HID, Wub, xg_u, bu_p,
        BATCH, GATE4, HID, GATE4, GATE4);

    // ---- rolling LSTM: step 0 pure cell (h=c=0), then 15 fused steps ----
    lstm_cell0_k<<<dim3(BATCH * HID / 256), blk, 0, stream>>>(xg_r, bhhr_p, c_buf, h0);
    unsigned short* hc = h0;
    unsigned short* hn = h1;
    for (int s = 1; s < SEQ; ++s) {
        lstm_step_fused<true><<<dim3(GATE4 / 64, BATCH / 64), blk, 0, stream>>>(
            hc, Whhrb, xg_r + (size_t)s * BATCH * GATE4, bhhr_p, c_buf, hn);
        unsigned short* tmp = hc; hc = hn; hn = tmp;
    }

    // ---- 2 unroll steps (bias folded into xg_u) ----
    for (int s = 0; s < 2; ++s) {
        lstm_step_fused<false><<<dim3(GATE4 / 64, BATCH / 64), blk, 0, stream>>>(
            hc, Whhub, xg_u, nullptr, c_buf, hn);
        unsigned short* tmp = hc; hc = hn; hn = tmp;
    }

    // ---- classifier: y = h @ Wc^T + bc -> fp32 [512,2513] ----
    gemm_bt<false, true, true, false><<<dim3(ACTP / 128, BATCH / 128), blk, 0, stream>>>(
        hc, Wcb, out, bc_p, BATCH, ACTP, HID, ACTN, ACTN);
}

// Round 15
// 434.685 us; speedup vs baseline: 1.1080x; 1.0151x over previous
//
#include <hip/hip_runtime.h>
#include <stdint.h>

// ---------------------------------------------------------------------------
// RULSTM collapsed: y = h2 @ Wc.T + bc, h2 = 2 unroll steps from rolling-LSTM
// final state. Gate axis permuted (n_new=(j&15)|gate<<4|(j>>4)<<6) so the LSTM
// cell fuses into the GEMM epilogue.
// r15 = best-of composition: gemm_bt r13-verbatim (2-phase dbuf BK=64, XOR
// swizzle, XCD 8x8 super-tiles; r14's counted-vmcnt variant REVERTED — it
// regressed G2 96.7->102.5) + step kernel r14-verbatim (r10 4-buf depth-3
// counted-vmcnt schedule + T5 setprio, which gained ~8us across 17 steps).
// ---------------------------------------------------------------------------

typedef __attribute__((ext_vector_type(8))) short short8;
typedef __attribute__((ext_vector_type(4))) float f32x4;

#define SEQ   16
#define BATCH 512
#define HID   1024
#define GATE4 4096
#define FEAT  2048
#define ACTN  2513
#define ACTP  2560
#define SB    (SEQ * BATCH)   // 8192

#define VMCNT0 asm volatile("s_waitcnt vmcnt(0)" ::: "memory")
#define BAR    __builtin_amdgcn_s_barrier()
#define SCHED0 __builtin_amdgcn_sched_barrier(0)
#define WAITV(n) asm volatile("s_waitcnt vmcnt(" #n ")" ::: "memory")

__device__ __forceinline__ unsigned short f2bf(float x) {
    unsigned u = __float_as_uint(x);
    u = u + 0x7FFFu + ((u >> 16) & 1u);
    return (unsigned short)(u >> 16);
}
__device__ __forceinline__ float bf2f(unsigned short h) {
    return __uint_as_float(((unsigned)h) << 16);
}
__device__ __forceinline__ float sigm(float x) { return 1.f / (1.f + __expf(-x)); }

__device__ __forceinline__ int gate_unperm(int nn) {
    return (((nn >> 4) & 3) << 10) | ((nn >> 6) << 4) | (nn & 15);
}

__device__ __forceinline__ void gload_lds16(const void* g, void* l) {
    __builtin_amdgcn_global_load_lds(
        (const __attribute__((address_space(1))) void*)g,
        (__attribute__((address_space(3))) void*)l,
        16, 0, 0);
}

// ---------------------------------------------------------------------------
// Generic C[M,N] = A[M,K]@W[N,K]^T (+bias), 128x128 tile, 2-phase dbuf,
// XOR-swizzled LDS (r7-proven), optional XCD-aware 8x8 super-tile swizzle
// (r13-proven). r13-verbatim.
// ---------------------------------------------------------------------------
template<bool OUT_BF16, bool HAS_BIAS, bool GUARD, bool SWZ>
__global__ __launch_bounds__(256)
void gemm_bt(const unsigned short* __restrict__ A,
             const unsigned short* __restrict__ W,
             void* __restrict__ Cv,
             const float* __restrict__ bias,
             int M, int N, int K, int ldc, int nvalid)
{
    __shared__ __align__(16) unsigned short sA[2][128 * 64];
    __shared__ __align__(16) unsigned short sB[2][128 * 64];

    int bxi, byi;
    if (SWZ) {
        const int bid = blockIdx.x;
        const int xcd = bid & 7;
        const int l   = bid >> 3;
        const int u   = l & 63;
        const int sl  = l >> 6;
        const int s   = xcd + 8 * sl;
        const int nxs = (N >> 7) >> 3;
        bxi = (s % nxs) * 8 + (u & 7);
        byi = (s / nxs) * 8 + (u >> 3);
    } else {
        bxi = blockIdx.x;
        byi = blockIdx.y;
    }

    const int t    = threadIdx.x;
    const int lane = t & 63;
    const int wave = t >> 6;
    const int m0   = byi * 128;
    const int n0   = bxi * 128;
    const int srow = t >> 3;                       // 0..31
    const int schk = t & 7;                        // linear LDS chunk
    const int swc  = (schk ^ (srow & 7)) * 8;      // swizzled global col (elems)
    const int sdst = srow * 64 + schk * 8;         // linear LDS dest (elems)
    const int wm   = (wave >> 1) * 64;
    const int wn   = (wave & 1) * 64;
    const int fl   = lane & 15;
    const int fk8  = (lane >> 4) * 8;              // 0 or 8
    const int l7   = lane & 7;                     // row&7 for fragment reads

    f32x4 acc[4][4] = {};

    const unsigned short* Abase = A + (size_t)(m0 + srow) * K + swc;
    const unsigned short* Wbase = W + (size_t)(n0 + srow) * K + swc;

    const int nkt = K >> 6;

#define G_STAGE(kt, buf)                                                     \
    {                                                                        \
        _Pragma("unroll")                                                    \
        for (int j = 0; j < 4; ++j) {                                        \
            gload_lds16(Abase + (size_t)j * 32 * K + (kt) * 64,              \
                        &sA[buf][sdst + j * 32 * 64]);                       \
            gload_lds16(Wbase + (size_t)j * 32 * K + (kt) * 64,              \
                        &sB[buf][sdst + j * 32 * 64]);                       \
        }                                                                    \
    }

    G_STAGE(0, 0);
    VMCNT0; BAR; SCHED0;

    int cur = 0;
    for (int kt = 0; kt < nkt; ++kt) {
        if (kt + 1 < nkt) G_STAGE(kt + 1, cur ^ 1);
        const unsigned short* sa = sA[cur];
        const unsigned short* sb = sB[cur];
#pragma unroll
        for (int kk = 0; kk < 64; kk += 32) {
            const int cs = (((kk + fk8) >> 3) ^ l7) * 8;  // swizzled read col
            short8 af[4], bfrag[4];
#pragma unroll
            for (int i = 0; i < 4; ++i)
                af[i] = *(const short8*)&sa[(wm + i * 16 + fl) * 64 + cs];
#pragma unroll
            for (int i = 0; i < 4; ++i)
                bfrag[i] = *(const short8*)&sb[(wn + i * 16 + fl) * 64 + cs];
#pragma unroll
            for (int mi = 0; mi < 4; ++mi)
#pragma unroll
                for (int ni = 0; ni < 4; ++ni)
                    acc[mi][ni] = __builtin_amdgcn_mfma_f32_16x16x32_bf16(
                        af[mi], bfrag[ni], acc[mi][ni], 0, 0, 0);
        }
        VMCNT0; BAR; SCHED0;
        cur ^= 1;
    }
#undef G_STAGE

    const int crb = (lane >> 4) * 4;
#pragma unroll
    for (int mi = 0; mi < 4; ++mi) {
#pragma unroll
        for (int ni = 0; ni < 4; ++ni) {
            const int col = n0 + wn + ni * 16 + fl;
            if (GUARD && col >= nvalid) continue;
            const float bv = HAS_BIAS ? bias[col] : 0.0f;
#pragma unroll
            for (int r = 0; r < 4; ++r) {
                const int row = m0 + wm + mi * 16 + crb + r;
                float v = acc[mi][ni][r] + bv;
                if (OUT_BF16)
                    ((unsigned short*)Cv)[(size_t)row * ldc + col] = f2bf(v);
                else
                    ((float*)Cv)[(size_t)row * ldc + col] = v;
            }
        }
    }
}

// ---------------------------------------------------------------------------
// Fused LSTM step: r10 schedule (64x64 tile, grid (64,8), 256 thr, 2 blk/CU,
// 4 LDS buffers, depth-3 counted-vmcnt) + T5 setprio (r14-proven, ~+0.5us/step).
// ---------------------------------------------------------------------------
template<bool HAS_BIAS>
__global__ __launch_bounds__(256)
void lstm_step_fused(const unsigned short* __restrict__ hin,  // [512,1024] bf16
                     const unsigned short* __restrict__ W,    // [4096,1024] perm
                     const unsigned short* __restrict__ xg,   // [512,4096] perm
                     const float* __restrict__ bias,          // [4096] perm/null
                     float* __restrict__ c,                   // [512,1024] f32
                     unsigned short* __restrict__ hout)       // [512,1024] bf16
{
    __shared__ __align__(16) unsigned short sA[4][64 * 64];   // 32 KiB
    __shared__ __align__(16) unsigned short sB[4][64 * 64];   // 32 KiB

    const int t    = threadIdx.x;
    const int lane = t & 63;
    const int wave = t >> 6;          // 0..3, 16 rows each
    const int m0   = blockIdx.y * 64;
    const int n0   = blockIdx.x * 64;
    const int srow = t >> 3;          // 0..31
    const int schk = t & 7;
    const int swc  = (schk ^ (srow & 7)) * 8;
    const int sdst = srow * 64 + schk * 8;
    const int wm   = wave * 16;
    const int fl   = lane & 15;
    const int fk8  = (lane >> 4) * 8;
    const int l7   = lane & 7;

    f32x4 acc[4] = {};

    const unsigned short* Abase = hin + (size_t)(m0 + srow) * HID + swc;
    const unsigned short* Wbase = W + (size_t)(n0 + srow) * HID + swc;

#define S_STAGE(kt)                                                          \
    {                                                                        \
        const int _b = (kt) & 3;                                             \
        _Pragma("unroll")                                                    \
        for (int j = 0; j < 2; ++j) {                                        \
            gload_lds16(Abase + (size_t)j * 32 * HID + (kt) * 64,            \
                        &sA[_b][sdst + j * 32 * 64]);                        \
            gload_lds16(Wbase + (size_t)j * 32 * HID + (kt) * 64,            \
                        &sB[_b][sdst + j * 32 * 64]);                        \
        }                                                                    \
    }

#define S_COMP(kt)                                                           \
    {                                                                        \
        const unsigned short* sa = sA[(kt) & 3];                             \
        const unsigned short* sb = sB[(kt) & 3];                             \
        __builtin_amdgcn_s_setprio(1);                                       \
        _Pragma("unroll")                                                    \
        for (int kk = 0; kk < 64; kk += 32) {                                \
            const int cs = (((kk + fk8) >> 3) ^ l7) * 8;                     \
            short8 af = *(const short8*)&sa[(wm + fl) * 64 + cs];            \
            _Pragma("unroll")                                                \
            for (int ni = 0; ni < 4; ++ni) {                                 \
                short8 bfr = *(const short8*)&sb[(ni * 16 + fl) * 64 + cs];  \
                acc[ni] = __builtin_amdgcn_mfma_f32_16x16x32_bf16(           \
                    af, bfr, acc[ni], 0, 0, 0);                              \
            }                                                                \
        }                                                                    \
        __builtin_amdgcn_s_setprio(0);                                       \
    }

    S_STAGE(0); S_STAGE(1); S_STAGE(2);      // 12 loads in flight
    for (int kt = 0; kt < 14; ++kt) {
        WAITV(8); BAR; SCHED0;               // stage(kt) resident; 8 in flight
        if (kt + 3 < 16) S_STAGE(kt + 3);    // refill into buffer freed @kt-1
        S_COMP(kt);
    }
    WAITV(4); BAR; SCHED0; S_COMP(14);
    WAITV(0); BAR; SCHED0; S_COMP(15);
#undef S_STAGE
#undef S_COMP

    // fused cell epilogue: ni = gate (0:i 1:f 2:g 3:o), j = (n0>>6)*16 + fl
    const int crb = (lane >> 4) * 4;
    const int jj  = (n0 >> 6) * 16 + fl;
    float bv[4] = {0.f, 0.f, 0.f, 0.f};
    if (HAS_BIAS) {
#pragma unroll
        for (int ni = 0; ni < 4; ++ni) bv[ni] = bias[n0 + ni * 16 + fl];
    }
#pragma unroll
    for (int r = 0; r < 4; ++r) {
        const int b = m0 + wm + crb + r;
        float v[4];
#pragma unroll
        for (int ni = 0; ni < 4; ++ni)
            v[ni] = acc[ni][r] + bv[ni] + bf2f(xg[(size_t)b * GATE4 + n0 + ni * 16 + fl]);
        const int ci = b * HID + jj;
        float cv = sigm(v[1]) * c[ci] + sigm(v[0]) * tanhf(v[2]);
        c[ci] = cv;
        hout[ci] = f2bf(sigm(v[3]) * tanhf(cv));
    }
}

// ---------------------------------------------------------------------------
// Step 0 of rolling LSTM (h=0, c=0): pure cell on xg_r[0] + bhh
// ---------------------------------------------------------------------------
__global__ void lstm_cell0_k(const unsigned short* __restrict__ xg,
                             const float* __restrict__ bias,
                             float* __restrict__ c, unsigned short* __restrict__ h)
{
    int idx = blockIdx.x * blockDim.x + threadIdx.x;  // < 512*1024
    int b = idx >> 10, j = idx & 1023;
    int base = (j & 15) | ((j >> 4) << 6);
    float v[4];
#pragma unroll
    for (int g = 0; g < 4; ++g) {
        int col = base | (g << 4);
        v[g] = bf2f(xg[(size_t)b * GATE4 + col]) + bias[col];
    }
    float cv = sigm(v[0]) * tanhf(v[2]);   // c_prev = 0
    c[idx] = cv;
    h[idx] = f2bf(sigm(v[3]) * tanhf(cv));
}

// ---------------------------------------------------------------------------
// One merged prep kernel (all conversions/permutations/folds)
// ---------------------------------------------------------------------------
#define PB_IN   16384
#define PB_W1   (PB_IN + 2048)       // 18432
#define PB_WR   (PB_W1 + 4096)       // 22528
#define PB_WU   (PB_WR + 4096)       // 26624
#define PB_WHR  (PB_WU + 4096)       // 30720
#define PB_WHU  (PB_WHR + 4096)      // 34816
#define PB_WC   (PB_WHU + 2560)      // 37376
#define PB_END  (PB_WC + 26)         // 37402

__device__ __forceinline__ void cvt4(const float* src, unsigned short* dst) {
    float4 v = *(const float4*)src;
    ushort4 o;
    o.x = f2bf(v.x); o.y = f2bf(v.y); o.z = f2bf(v.z); o.w = f2bf(v.w);
    *(ushort4*)dst = o;
}

__global__ void prep_all_k(const float* __restrict__ inputs, const float* __restrict__ W1,
                           const float* __restrict__ Wih_r, const float* __restrict__ Wih_u,
                           const float* __restrict__ Whh_r, const float* __restrict__ Whh_u,
                           const float* __restrict__ Wc,
                           const float* __restrict__ bih_r, const float* __restrict__ bhh_r,
                           const float* __restrict__ bih_u, const float* __restrict__ bhh_u,
                           const float* __restrict__ bc,
                           unsigned short* __restrict__ in_bf, unsigned short* __restrict__ W1b,
                           unsigned short* __restrict__ Wrb, unsigned short* __restrict__ Wub,
                           unsigned short* __restrict__ Whhrb, unsigned short* __restrict__ Whhub,
                           unsigned short* __restrict__ Wcb,
                           float* __restrict__ bihr_p, float* __restrict__ bhhr_p,
                           float* __restrict__ bu_p, float* __restrict__ bc_p)
{
    const int blk = blockIdx.x, tid = threadIdx.x;
    if (blk < PB_IN) {                       // inputs f32 -> bf16 (8192x2048)
        int i = blk * 256 + tid;
        cvt4(inputs + (size_t)i * 4, in_bf + (size_t)i * 4);
    } else if (blk < PB_W1) {                // W1 f32 -> bf16 (1024x2048)
        int i = (blk - PB_IN) * 256 + tid;
        cvt4(W1 + (size_t)i * 4, W1b + (size_t)i * 4);
    } else if (blk < PB_WR) {                // Wih_r: sum halves + perm
        int i = (blk - PB_W1) * 256 + tid;
        int nn = i >> 8, k4 = (i & 255) * 4;
        const float* row = Wih_r + (size_t)gate_unperm(nn) * FEAT;
        float4 a = *(const float4*)(row + k4);
        float4 b = *(const float4*)(row + HID + k4);
        ushort4 o;
        o.x = f2bf(a.x + b.x); o.y = f2bf(a.y + b.y);
        o.z = f2bf(a.z + b.z); o.w = f2bf(a.w + b.w);
        *(ushort4*)(Wrb + (size_t)nn * HID + k4) = o;
    } else if (blk < PB_WU) {                // Wih_u: sum halves + perm
        int i = (blk - PB_WR) * 256 + tid;
        int nn = i >> 8, k4 = (i & 255) * 4;
        const float* row = Wih_u + (size_t)gate_unperm(nn) * FEAT;
        float4 a = *(const float4*)(row + k4);
        float4 b = *(const float4*)(row + HID + k4);
        ushort4 o;
        o.x = f2bf(a.x + b.x); o.y = f2bf(a.y + b.y);
        o.z = f2bf(a.z + b.z); o.w = f2bf(a.w + b.w);
        *(ushort4*)(Wub + (size_t)nn * HID + k4) = o;
    } else if (blk < PB_WHR) {               // Whh_r perm
        int i = (blk - PB_WU) * 256 + tid;
        int nn = i >> 8, k4 = (i & 255) * 4;
        cvt4(Whh_r + (size_t)gate_unperm(nn) * HID + k4, Whhrb + (size_t)nn * HID + k4);
    } else if (blk < PB_WHU) {               // Whh_u perm
        int i = (blk - PB_WHR) * 256 + tid;
        int nn = i >> 8, k4 = (i & 255) * 4;
        cvt4(Whh_u + (size_t)gate_unperm(nn) * HID + k4, Whhub + (size_t)nn * HID + k4);
    } else if (blk < PB_WC) {                // Wc pad to 2560 rows
        int i = (blk - PB_WHU) * 256 + tid;
        int g = i >> 8, k4 = (i & 255) * 4;
        if (g < ACTN) {
            cvt4(Wc + (size_t)g * HID + k4, Wcb + (size_t)g * HID + k4);
        } else {
            ushort4 o; o.x = o.y = o.z = o.w = 0;
            *(ushort4*)(Wcb + (size_t)g * HID + k4) = o;
        }
    } else {                                 // biases (4096 perm + 2560 bc)
        int i = (blk - PB_WC) * 256 + tid;
        if (i < GATE4) {
            int src = gate_unperm(i);
            bihr_p[i] = bih_r[src];
            bhhr_p[i] = bhh_r[src];
            bu_p[i]   = bih_u[src] + bhh_u[src];
        } else if (i < GATE4 + ACTP) {
            int j = i - GATE4;
            bc_p[j] = (j < ACTN) ? bc[j] : 0.f;
        }
    }
}

// ---------------------------------------------------------------------------
// Workspace layout (bytes) — end 162,588,672 (proven footprint)
// ---------------------------------------------------------------------------
#define OFF_IN_BF 0ull
#define OFF_X_BF  33554432ull
#define OFF_XGR   50331648ull
#define OFF_W1    117440512ull
#define OFF_WR    121634816ull
#define OFF_WHHR  130023424ull
#define OFF_WU    138412032ull
#define OFF_WHHU  146800640ull
#define OFF_WCB   155189248ull      // 2560*1024*2 -> ends 160432128
#define OFF_H0    160432128ull      // 1 MiB
#define OFF_H1    161480704ull      // 1 MiB
#define OFF_BC    162529280ull
#define OFF_BU    162539520ull
#define OFF_BIHR  162555904ull
#define OFF_BHHR  162572288ull
// xg_u (4 MiB) and c_buf (2 MiB) overlay in_bf (dead after G1).

extern "C" void kernel_launch(void* const* d_in, const int* in_sizes, int n_in,
                              void* d_out, int out_size, void* d_ws, size_t ws_size,
                              hipStream_t stream)
{
    const float* inputs = (const float*)d_in[0];
    const float* W1     = (const float*)d_in[1];
    const float* b1     = (const float*)d_in[2];
    const float* Wih_r  = (const float*)d_in[3];
    const float* Whh_r  = (const float*)d_in[4];
    const float* bih_r  = (const float*)d_in[5];
    const float* bhh_r  = (const float*)d_in[6];
    const float* Wih_u  = (const float*)d_in[7];
    const float* Whh_u  = (const float*)d_in[8];
    const float* bih_u  = (const float*)d_in[9];
    const float* bhh_u  = (const float*)d_in[10];
    const float* Wc     = (const float*)d_in[11];
    const float* bc     = (const float*)d_in[12];
    float* out = (float*)d_out;
    char* ws = (char*)d_ws;

    unsigned short* in_bf = (unsigned short*)(ws + OFF_IN_BF);
    unsigned short* x_bf  = (unsigned short*)(ws + OFF_X_BF);
    unsigned short* xg_r  = (unsigned short*)(ws + OFF_XGR);
    unsigned short* W1b   = (unsigned short*)(ws + OFF_W1);
    unsigned short* Wrb   = (unsigned short*)(ws + OFF_WR);
    unsigned short* Whhrb = (unsigned short*)(ws + OFF_WHHR);
    unsigned short* Wub   = (unsigned short*)(ws + OFF_WU);
    unsigned short* Whhub = (unsigned short*)(ws + OFF_WHHU);
    unsigned short* Wcb   = (unsigned short*)(ws + OFF_WCB);
    unsigned short* h0    = (unsigned short*)(ws + OFF_H0);
    unsigned short* h1    = (unsigned short*)(ws + OFF_H1);
    float*          bc_p  = (float*)(ws + OFF_BC);
    float*          bu_p  = (float*)(ws + OFF_BU);
    float*          bihr_p= (float*)(ws + OFF_BIHR);
    float*          bhhr_p= (float*)(ws + OFF_BHHR);
    unsigned short* xg_u  = (unsigned short*)(ws + OFF_IN_BF);           // 4 MiB
    float*          c_buf = (float*)(ws + OFF_IN_BF + 4194304ull);      // 2 MiB

    const dim3 blk(256);

    // ---- prep (one launch) ----
    prep_all_k<<<dim3(PB_END), blk, 0, stream>>>(
        inputs, W1, Wih_r, Wih_u, Whh_r, Whh_u, Wc,
        bih_r, bhh_r, bih_u, bhh_u, bc,
        in_bf, W1b, Wrb, Wub, Whhrb, Whhub, Wcb,
        bihr_p, bhhr_p, bu_p, bc_p);

    // ---- G1: x = inputs @ W1^T + b1 -> bf16 [8192,1024]  (XCD-swizzled) ----
    gemm_bt<true, true, false, true><<<dim3((HID / 128) * (SB / 128)), blk, 0, stream>>>(
        in_bf, W1b, x_bf, b1, SB, HID, FEAT, HID, HID);

    // ---- G2: xg_r = x @ Wr_eff^T + bih_r -> bf16 [8192,4096] (XCD-swizzled) ----
    gemm_bt<true, true, false, true><<<dim3((GATE4 / 128) * (SB / 128)), blk, 0, stream>>>(
        x_bf, Wrb, xg_r, bihr_p, SB, GATE4, HID, GATE4, GATE4);

    // ---- xg_u = x[15] @ Wu_eff^T + (bih_u + bhh_u) -> bf16 [512,4096] ----
    gemm_bt<true, true, false, false><<<dim3(GATE4 / 128, BATCH / 128), blk, 0, stream>>>(
        x_bf + (size_t)(SEQ - 1) * BATCH * HID, Wub, xg_u, bu_p,
        BATCH, GATE4, HID, GATE4, GATE4);

    // ---- rolling LSTM: step 0 pure cell (h=c=0), then 15 fused steps ----
    lstm_cell0_k<<<dim3(BATCH * HID / 256), blk, 0, stream>>>(xg_r, bhhr_p, c_buf, h0);
    unsigned short* hc = h0;
    unsigned short* hn = h1;
    for (int s = 1; s < SEQ; ++s) {
        lstm_step_fused<true><<<dim3(GATE4 / 64, BATCH / 64), blk, 0, stream>>>(
            hc, Whhrb, xg_r + (size_t)s * BATCH * GATE4, bhhr_p, c_buf, hn);
        unsigned short* tmp = hc; hc = hn; hn = tmp;
    }

    // ---- 2 unroll steps (bias folded into xg_u) ----
    for (int s = 0; s < 2; ++s) {
        lstm_step_fused<false><<<dim3(GATE4 / 64, BATCH / 64), blk, 0, stream>>>(
            hc, Whhub, xg_u, nullptr, c_buf, hn);
        unsigned short* tmp = hc; hc = hn; hn = tmp;
    }

    // ---- classifier: y = h @ Wc^T + bc -> fp32 [512,2513] ----
    gemm_bt<false, true, true, false><<<dim3(ACTP / 128, BATCH / 128), blk, 0, stream>>>(
        hc, Wcb, out, bc_p, BATCH, ACTP, HID, ACTN, ACTN);
}

// Round 16
// 411.770 us; speedup vs baseline: 1.1697x; 1.0556x over previous
//
#include <hip/hip_runtime.h>
#include <stdint.h>

// ---------------------------------------------------------------------------
// RULSTM collapsed: y = h2 @ Wc.T + bc, h2 = 2 unroll steps from rolling-LSTM
// final state. Gate axis permuted (n_new=(j&15)|gate<<4|(j>>4)<<6) so the LSTM
// cell fuses into the GEMM epilogue.
// r16 = r15 (best, 434.7us) + ONE change: XCD-aware swizzle on the step-kernel
// grid (1-D 512 blocks; XCD x owns gate-slices bx in [8x,8x+8) x all 8 batch
// blocks) -> per-XCD W working set 8MB -> 1MB, L2-resident ACROSS the 15
// rolling steps (same Whhr re-read every launch). Pure bijective index remap.
// ---------------------------------------------------------------------------

typedef __attribute__((ext_vector_type(8))) short short8;
typedef __attribute__((ext_vector_type(4))) float f32x4;

#define SEQ   16
#define BATCH 512
#define HID   1024
#define GATE4 4096
#define FEAT  2048
#define ACTN  2513
#define ACTP  2560
#define SB    (SEQ * BATCH)   // 8192

#define VMCNT0 asm volatile("s_waitcnt vmcnt(0)" ::: "memory")
#define BAR    __builtin_amdgcn_s_barrier()
#define SCHED0 __builtin_amdgcn_sched_barrier(0)
#define WAITV(n) asm volatile("s_waitcnt vmcnt(" #n ")" ::: "memory")

__device__ __forceinline__ unsigned short f2bf(float x) {
    unsigned u = __float_as_uint(x);
    u = u + 0x7FFFu + ((u >> 16) & 1u);
    return (unsigned short)(u >> 16);
}
__device__ __forceinline__ float bf2f(unsigned short h) {
    return __uint_as_float(((unsigned)h) << 16);
}
__device__ __forceinline__ float sigm(float x) { return 1.f / (1.f + __expf(-x)); }

__device__ __forceinline__ int gate_unperm(int nn) {
    return (((nn >> 4) & 3) << 10) | ((nn >> 6) << 4) | (nn & 15);
}

__device__ __forceinline__ void gload_lds16(const void* g, void* l) {
    __builtin_amdgcn_global_load_lds(
        (const __attribute__((address_space(1))) void*)g,
        (__attribute__((address_space(3))) void*)l,
        16, 0, 0);
}

// ---------------------------------------------------------------------------
// Generic C[M,N] = A[M,K]@W[N,K]^T (+bias), 128x128 tile, 2-phase dbuf,
// XOR-swizzled LDS (r7-proven), optional XCD-aware 8x8 super-tile swizzle
// (r13-proven). r13-verbatim.
// ---------------------------------------------------------------------------
template<bool OUT_BF16, bool HAS_BIAS, bool GUARD, bool SWZ>
__global__ __launch_bounds__(256)
void gemm_bt(const unsigned short* __restrict__ A,
             const unsigned short* __restrict__ W,
             void* __restrict__ Cv,
             const float* __restrict__ bias,
             int M, int N, int K, int ldc, int nvalid)
{
    __shared__ __align__(16) unsigned short sA[2][128 * 64];
    __shared__ __align__(16) unsigned short sB[2][128 * 64];

    int bxi, byi;
    if (SWZ) {
        const int bid = blockIdx.x;
        const int xcd = bid & 7;
        const int l   = bid >> 3;
        const int u   = l & 63;
        const int sl  = l >> 6;
        const int s   = xcd + 8 * sl;
        const int nxs = (N >> 7) >> 3;
        bxi = (s % nxs) * 8 + (u & 7);
        byi = (s / nxs) * 8 + (u >> 3);
    } else {
        bxi = blockIdx.x;
        byi = blockIdx.y;
    }

    const int t    = threadIdx.x;
    const int lane = t & 63;
    const int wave = t >> 6;
    const int m0   = byi * 128;
    const int n0   = bxi * 128;
    const int srow = t >> 3;                       // 0..31
    const int schk = t & 7;                        // linear LDS chunk
    const int swc  = (schk ^ (srow & 7)) * 8;      // swizzled global col (elems)
    const int sdst = srow * 64 + schk * 8;         // linear LDS dest (elems)
    const int wm   = (wave >> 1) * 64;
    const int wn   = (wave & 1) * 64;
    const int fl   = lane & 15;
    const int fk8  = (lane >> 4) * 8;              // 0 or 8
    const int l7   = lane & 7;                     // row&7 for fragment reads

    f32x4 acc[4][4] = {};

    const unsigned short* Abase = A + (size_t)(m0 + srow) * K + swc;
    const unsigned short* Wbase = W + (size_t)(n0 + srow) * K + swc;

    const int nkt = K >> 6;

#define G_STAGE(kt, buf)                                                     \
    {                                                                        \
        _Pragma("unroll")                                                    \
        for (int j = 0; j < 4; ++j) {                                        \
            gload_lds16(Abase + (size_t)j * 32 * K + (kt) * 64,              \
                        &sA[buf][sdst + j * 32 * 64]);                       \
            gload_lds16(Wbase + (size_t)j * 32 * K + (kt) * 64,              \
                        &sB[buf][sdst + j * 32 * 64]);                       \
        }                                                                    \
    }

    G_STAGE(0, 0);
    VMCNT0; BAR; SCHED0;

    int cur = 0;
    for (int kt = 0; kt < nkt; ++kt) {
        if (kt + 1 < nkt) G_STAGE(kt + 1, cur ^ 1);
        const unsigned short* sa = sA[cur];
        const unsigned short* sb = sB[cur];
#pragma unroll
        for (int kk = 0; kk < 64; kk += 32) {
            const int cs = (((kk + fk8) >> 3) ^ l7) * 8;  // swizzled read col
            short8 af[4], bfrag[4];
#pragma unroll
            for (int i = 0; i < 4; ++i)
                af[i] = *(const short8*)&sa[(wm + i * 16 + fl) * 64 + cs];
#pragma unroll
            for (int i = 0; i < 4; ++i)
                bfrag[i] = *(const short8*)&sb[(wn + i * 16 + fl) * 64 + cs];
#pragma unroll
            for (int mi = 0; mi < 4; ++mi)
#pragma unroll
                for (int ni = 0; ni < 4; ++ni)
                    acc[mi][ni] = __builtin_amdgcn_mfma_f32_16x16x32_bf16(
                        af[mi], bfrag[ni], acc[mi][ni], 0, 0, 0);
        }
        VMCNT0; BAR; SCHED0;
        cur ^= 1;
    }
#undef G_STAGE

    const int crb = (lane >> 4) * 4;
#pragma unroll
    for (int mi = 0; mi < 4; ++mi) {
#pragma unroll
        for (int ni = 0; ni < 4; ++ni) {
            const int col = n0 + wn + ni * 16 + fl;
            if (GUARD && col >= nvalid) continue;
            const float bv = HAS_BIAS ? bias[col] : 0.0f;
#pragma unroll
            for (int r = 0; r < 4; ++r) {
                const int row = m0 + wm + mi * 16 + crb + r;
                float v = acc[mi][ni][r] + bv;
                if (OUT_BF16)
                    ((unsigned short*)Cv)[(size_t)row * ldc + col] = f2bf(v);
                else
                    ((float*)Cv)[(size_t)row * ldc + col] = v;
            }
        }
    }
}

// ---------------------------------------------------------------------------
// Fused LSTM step: r10 schedule (64x64 tile, 512 blocks, 256 thr, 2 blk/CU,
// 4 LDS buffers, depth-3 counted-vmcnt) + T5 setprio (r14-proven) + NEW:
// XCD-aware 1-D grid swizzle (XCD x owns bx in [8x,8x+8) -> 1MB W/XCD,
// L2-resident across steps).
// ---------------------------------------------------------------------------
template<bool HAS_BIAS>
__global__ __launch_bounds__(256)
void lstm_step_fused(const unsigned short* __restrict__ hin,  // [512,1024] bf16
                     const unsigned short* __restrict__ W,    // [4096,1024] perm
                     const unsigned short* __restrict__ xg,   // [512,4096] perm
                     const float* __restrict__ bias,          // [4096] perm/null
                     float* __restrict__ c,                   // [512,1024] f32
                     unsigned short* __restrict__ hout)       // [512,1024] bf16
{
    __shared__ __align__(16) unsigned short sA[4][64 * 64];   // 32 KiB
    __shared__ __align__(16) unsigned short sB[4][64 * 64];   // 32 KiB

    // XCD swizzle: xcd = bid&7 owns gate-slices bx = xcd*8 + 0..7
    const int bid = blockIdx.x;                   // 0..511
    const int xcd = bid & 7;
    const int li  = bid >> 3;                     // 0..63
    const int bx  = xcd * 8 + (li & 7);           // 0..63 (gate-col block)
    const int by  = li >> 3;                      // 0..7  (batch block)

    const int t    = threadIdx.x;
    const int lane = t & 63;
    const int wave = t >> 6;          // 0..3, 16 rows each
    const int m0   = by * 64;
    const int n0   = bx * 64;
    const int srow = t >> 3;          // 0..31
    const int schk = t & 7;
    const int swc  = (schk ^ (srow & 7)) * 8;
    const int sdst = srow * 64 + schk * 8;
    const int wm   = wave * 16;
    const int fl   = lane & 15;
    const int fk8  = (lane >> 4) * 8;
    const int l7   = lane & 7;

    f32x4 acc[4] = {};

    const unsigned short* Abase = hin + (size_t)(m0 + srow) * HID + swc;
    const unsigned short* Wbase = W + (size_t)(n0 + srow) * HID + swc;

#define S_STAGE(kt)                                                          \
    {                                                                        \
        const int _b = (kt) & 3;                                             \
        _Pragma("unroll")                                                    \
        for (int j = 0; j < 2; ++j) {                                        \
            gload_lds16(Abase + (size_t)j * 32 * HID + (kt) * 64,            \
                        &sA[_b][sdst + j * 32 * 64]);                        \
            gload_lds16(Wbase + (size_t)j * 32 * HID + (kt) * 64,            \
                        &sB[_b][sdst + j * 32 * 64]);                        \
        }                                                                    \
    }

#define S_COMP(kt)                                                           \
    {                                                                        \
        const unsigned short* sa = sA[(kt) & 3];                             \
        const unsigned short* sb = sB[(kt) & 3];                             \
        __builtin_amdgcn_s_setprio(1);                                       \
        _Pragma("unroll")                                                    \
        for (int kk = 0; kk < 64; kk += 32) {                                \
            const int cs = (((kk + fk8) >> 3) ^ l7) * 8;                     \
            short8 af = *(const short8*)&sa[(wm + fl) * 64 + cs];            \
            _Pragma("unroll")                                                \
            for (int ni = 0; ni < 4; ++ni) {                                 \
                short8 bfr = *(const short8*)&sb[(ni * 16 + fl) * 64 + cs];  \
                acc[ni] = __builtin_amdgcn_mfma_f32_16x16x32_bf16(           \
                    af, bfr, acc[ni], 0, 0, 0);                              \
            }                                                                \
        }                                                                    \
        __builtin_amdgcn_s_setprio(0);                                       \
    }

    S_STAGE(0); S_STAGE(1); S_STAGE(2);      // 12 loads in flight
    for (int kt = 0; kt < 14; ++kt) {
        WAITV(8); BAR; SCHED0;               // stage(kt) resident; 8 in flight
        if (kt + 3 < 16) S_STAGE(kt + 3);    // refill into buffer freed @kt-1
        S_COMP(kt);
    }
    WAITV(4); BAR; SCHED0; S_COMP(14);
    WAITV(0); BAR; SCHED0; S_COMP(15);
#undef S_STAGE
#undef S_COMP

    // fused cell epilogue: ni = gate (0:i 1:f 2:g 3:o), j = bx*16 + fl
    const int crb = (lane >> 4) * 4;
    const int jj  = bx * 16 + fl;
    float bv[4] = {0.f, 0.f, 0.f, 0.f};
    if (HAS_BIAS) {
#pragma unroll
        for (int ni = 0; ni < 4; ++ni) bv[ni] = bias[n0 + ni * 16 + fl];
    }
#pragma unroll
    for (int r = 0; r < 4; ++r) {
        const int b = m0 + wm + crb + r;
        float v[4];
#pragma unroll
        for (int ni = 0; ni < 4; ++ni)
            v[ni] = acc[ni][r] + bv[ni] + bf2f(xg[(size_t)b * GATE4 + n0 + ni * 16 + fl]);
        const int ci = b * HID + jj;
        float cv = sigm(v[1]) * c[ci] + sigm(v[0]) * tanhf(v[2]);
        c[ci] = cv;
        hout[ci] = f2bf(sigm(v[3]) * tanhf(cv));
    }
}

// ---------------------------------------------------------------------------
// Step 0 of rolling LSTM (h=0, c=0): pure cell on xg_r[0] + bhh
// ---------------------------------------------------------------------------
__global__ void lstm_cell0_k(const unsigned short* __restrict__ xg,
                             const float* __restrict__ bias,
                             float* __restrict__ c, unsigned short* __restrict__ h)
{
    int idx = blockIdx.x * blockDim.x + threadIdx.x;  // < 512*1024
    int b = idx >> 10, j = idx & 1023;
    int base = (j & 15) | ((j >> 4) << 6);
    float v[4];
#pragma unroll
    for (int g = 0; g < 4; ++g) {
        int col = base | (g << 4);
        v[g] = bf2f(xg[(size_t)b * GATE4 + col]) + bias[col];
    }
    float cv = sigm(v[0]) * tanhf(v[2]);   // c_prev = 0
    c[idx] = cv;
    h[idx] = f2bf(sigm(v[3]) * tanhf(cv));
}

// ---------------------------------------------------------------------------
// One merged prep kernel (all conversions/permutations/folds)
// ---------------------------------------------------------------------------
#define PB_IN   16384
#define PB_W1   (PB_IN + 2048)       // 18432
#define PB_WR   (PB_W1 + 4096)       // 22528
#define PB_WU   (PB_WR + 4096)       // 26624
#define PB_WHR  (PB_WU + 4096)       // 30720
#define PB_WHU  (PB_WHR + 4096)      // 34816
#define PB_WC   (PB_WHU + 2560)      // 37376
#define PB_END  (PB_WC + 26)         // 37402

__device__ __forceinline__ void cvt4(const float* src, unsigned short* dst) {
    float4 v = *(const float4*)src;
    ushort4 o;
    o.x = f2bf(v.x); o.y = f2bf(v.y); o.z = f2bf(v.z); o.w = f2bf(v.w);
    *(ushort4*)dst = o;
}

__global__ void prep_all_k(const float* __restrict__ inputs, const float* __restrict__ W1,
                           const float* __restrict__ Wih_r, const float* __restrict__ Wih_u,
                           const float* __restrict__ Whh_r, const float* __restrict__ Whh_u,
                           const float* __restrict__ Wc,
                           const float* __restrict__ bih_r, const float* __restrict__ bhh_r,
                           const float* __restrict__ bih_u, const float* __restrict__ bhh_u,
                           const float* __restrict__ bc,
                           unsigned short* __restrict__ in_bf, unsigned short* __restrict__ W1b,
                           unsigned short* __restrict__ Wrb, unsigned short* __restrict__ Wub,
                           unsigned short* __restrict__ Whhrb, unsigned short* __restrict__ Whhub,
                           unsigned short* __restrict__ Wcb,
                           float* __restrict__ bihr_p, float* __restrict__ bhhr_p,
                           float* __restrict__ bu_p, float* __restrict__ bc_p)
{
    const int blk = blockIdx.x, tid = threadIdx.x;
    if (blk < PB_IN) {                       // inputs f32 -> bf16 (8192x2048)
        int i = blk * 256 + tid;
        cvt4(inputs + (size_t)i * 4, in_bf + (size_t)i * 4);
    } else if (blk < PB_W1) {                // W1 f32 -> bf16 (1024x2048)
        int i = (blk - PB_IN) * 256 + tid;
        cvt4(W1 + (size_t)i * 4, W1b + (size_t)i * 4);
    } else if (blk < PB_WR) {                // Wih_r: sum halves + perm
        int i = (blk - PB_W1) * 256 + tid;
        int nn = i >> 8, k4 = (i & 255) * 4;
        const float* row = Wih_r + (size_t)gate_unperm(nn) * FEAT;
        float4 a = *(const float4*)(row + k4);
        float4 b = *(const float4*)(row + HID + k4);
        ushort4 o;
        o.x = f2bf(a.x + b.x); o.y = f2bf(a.y + b.y);
        o.z = f2bf(a.z + b.z); o.w = f2bf(a.w + b.w);
        *(ushort4*)(Wrb + (size_t)nn * HID + k4) = o;
    } else if (blk < PB_WU) {                // Wih_u: sum halves + perm
        int i = (blk - PB_WR) * 256 + tid;
        int nn = i >> 8, k4 = (i & 255) * 4;
        const float* row = Wih_u + (size_t)gate_unperm(nn) * FEAT;
        float4 a = *(const float4*)(row + k4);
        float4 b = *(const float4*)(row + HID + k4);
        ushort4 o;
        o.x = f2bf(a.x + b.x); o.y = f2bf(a.y + b.y);
        o.z = f2bf(a.z + b.z); o.w = f2bf(a.w + b.w);
        *(ushort4*)(Wub + (size_t)nn * HID + k4) = o;
    } else if (blk < PB_WHR) {               // Whh_r perm
        int i = (blk - PB_WU) * 256 + tid;
        int nn = i >> 8, k4 = (i & 255) * 4;
        cvt4(Whh_r + (size_t)gate_unperm(nn) * HID + k4, Whhrb + (size_t)nn * HID + k4);
    } else if (blk < PB_WHU) {               // Whh_u perm
        int i = (blk - PB_WHR) * 256 + tid;
        int nn = i >> 8, k4 = (i & 255) * 4;
        cvt4(Whh_u + (size_t)gate_unperm(nn) * HID + k4, Whhub + (size_t)nn * HID + k4);
    } else if (blk < PB_WC) {                // Wc pad to 2560 rows
        int i = (blk - PB_WHU) * 256 + tid;
        int g = i >> 8, k4 = (i & 255) * 4;
        if (g < ACTN) {
            cvt4(Wc + (size_t)g * HID + k4, Wcb + (size_t)g * HID + k4);
        } else {
            ushort4 o; o.x = o.y = o.z = o.w = 0;
            *(ushort4*)(Wcb + (size_t)g * HID + k4) = o;
        }
    } else {                                 // biases (4096 perm + 2560 bc)
        int i = (blk - PB_WC) * 256 + tid;
        if (i < GATE4) {
            int src = gate_unperm(i);
            bihr_p[i] = bih_r[src];
            bhhr_p[i] = bhh_r[src];
            bu_p[i]   = bih_u[src] + bhh_u[src];
        } else if (i < GATE4 + ACTP) {
            int j = i - GATE4;
            bc_p[j] = (j < ACTN) ? bc[j] : 0.f;
        }
    }
}

// ---------------------------------------------------------------------------
// Workspace layout (bytes) — end 162,588,672 (proven footprint)
// ---------------------------------------------------------------------------
#define OFF_IN_BF 0ull
#define OFF_X_BF  33554432ull
#define OFF_XGR   50331648ull
#define OFF_W1    117440512ull
#define OFF_WR    121634816ull
#define OFF_WHHR  130023424ull
#define OFF_WU    138412032ull
#define OFF_WHHU  146800640ull
#define OFF_WCB   155189248ull      // 2560*1024*2 -> ends 160432128
#define OFF_H0    160432128ull      // 1 MiB
#define OFF_H1    161480704ull      // 1 MiB
#define OFF_BC    162529280ull
#define OFF_BU    162539520ull
#define OFF_BIHR  162555904ull
#define OFF_BHHR  162572288ull
// xg_u (4 MiB) and c_buf (2 MiB) overlay in_bf (dead after G1).

extern "C" void kernel_launch(void* const* d_in, const int* in_sizes, int n_in,
                              void* d_out, int out_size, void* d_ws, size_t ws_size,
                              hipStream_t stream)
{
    const float* inputs = (const float*)d_in[0];
    const float* W1     = (const float*)d_in[1];
    const float* b1     = (const float*)d_in[2];
    const float* Wih_r  = (const float*)d_in[3];
    const float* Whh_r  = (const float*)d_in[4];
    const float* bih_r  = (const float*)d_in[5];
    const float* bhh_r  = (const float*)d_in[6];
    const float* Wih_u  = (const float*)d_in[7];
    const float* Whh_u  = (const float*)d_in[8];
    const float* bih_u  = (const float*)d_in[9];
    const float* bhh_u  = (const float*)d_in[10];
    const float* Wc     = (const float*)d_in[11];
    const float* bc     = (const float*)d_in[12];
    float* out = (float*)d_out;
    char* ws = (char*)d_ws;

    unsigned short* in_bf = (unsigned short*)(ws + OFF_IN_BF);
    unsigned short* x_bf  = (unsigned short*)(ws + OFF_X_BF);
    unsigned short* xg_r  = (unsigned short*)(ws + OFF_XGR);
    unsigned short* W1b   = (unsigned short*)(ws + OFF_W1);
    unsigned short* Wrb   = (unsigned short*)(ws + OFF_WR);
    unsigned short* Whhrb = (unsigned short*)(ws + OFF_WHHR);
    unsigned short* Wub   = (unsigned short*)(ws + OFF_WU);
    unsigned short* Whhub = (unsigned short*)(ws + OFF_WHHU);
    unsigned short* Wcb   = (unsigned short*)(ws + OFF_WCB);
    unsigned short* h0    = (unsigned short*)(ws + OFF_H0);
    unsigned short* h1    = (unsigned short*)(ws + OFF_H1);
    float*          bc_p  = (float*)(ws + OFF_BC);
    float*          bu_p  = (float*)(ws + OFF_BU);
    float*          bihr_p= (float*)(ws + OFF_BIHR);
    float*          bhhr_p= (float*)(ws + OFF_BHHR);
    unsigned short* xg_u  = (unsigned short*)(ws + OFF_IN_BF);           // 4 MiB
    float*          c_buf = (float*)(ws + OFF_IN_BF + 4194304ull);      // 2 MiB

    const dim3 blk(256);

    // ---- prep (one launch) ----
    prep_all_k<<<dim3(PB_END), blk, 0, stream>>>(
        inputs, W1, Wih_r, Wih_u, Whh_r, Whh_u, Wc,
        bih_r, bhh_r, bih_u, bhh_u, bc,
        in_bf, W1b, Wrb, Wub, Whhrb, Whhub, Wcb,
        bihr_p, bhhr_p, bu_p, bc_p);

    // ---- G1: x = inputs @ W1^T + b1 -> bf16 [8192,1024]  (XCD-swizzled) ----
    gemm_bt<true, true, false, true><<<dim3((HID / 128) * (SB / 128)), blk, 0, stream>>>(
        in_bf, W1b, x_bf, b1, SB, HID, FEAT, HID, HID);

    // ---- G2: xg_r = x @ Wr_eff^T + bih_r -> bf16 [8192,4096] (XCD-swizzled) ----
    gemm_bt<true, true, false, true><<<dim3((GATE4 / 128) * (SB / 128)), blk, 0, stream>>>(
        x_bf, Wrb, xg_r, bihr_p, SB, GATE4, HID, GATE4, GATE4);

    // ---- xg_u = x[15] @ Wu_eff^T + (bih_u + bhh_u) -> bf16 [512,4096] ----
    gemm_bt<true, true, false, false><<<dim3(GATE4 / 128, BATCH / 128), blk, 0, stream>>>(
        x_bf + (size_t)(SEQ - 1) * BATCH * HID, Wub, xg_u, bu_p,
        BATCH, GATE4, HID, GATE4, GATE4);

    // ---- rolling LSTM: step 0 pure cell (h=c=0), then 15 fused steps ----
    lstm_cell0_k<<<dim3(BATCH * HID / 256), blk, 0, stream>>>(xg_r, bhhr_p, c_buf, h0);
    unsigned short* hc = h0;
    unsigned short* hn = h1;
    for (int s = 1; s < SEQ; ++s) {
        lstm_step_fused<true><<<dim3(512), blk, 0, stream>>>(
            hc, Whhrb, xg_r + (size_t)s * BATCH * GATE4, bhhr_p, c_buf, hn);
        unsigned short* tmp = hc; hc = hn; hn = tmp;
    }

    // ---- 2 unroll steps (bias folded into xg_u) ----
    for (int s = 0; s < 2; ++s) {
        lstm_step_fused<false><<<dim3(512), blk, 0, stream>>>(
            hc, Whhub, xg_u, nullptr, c_buf, hn);
        unsigned short* tmp = hc; hc = hn; hn = tmp;
    }

    // ---- classifier: y = h @ Wc^T + bc -> fp32 [512,2513] ----
    gemm_bt<false, true, true, false><<<dim3(ACTP / 128, BATCH / 128), blk, 0, stream>>>(
        hc, Wcb, out, bc_p, BATCH, ACTP, HID, ACTN, ACTN);
}